// Round 2
// baseline (1620.136 us; speedup 1.0000x reference)
//
#include <hip/hip_runtime.h>
#include <hip/hip_bf16.h>

typedef unsigned short u16;
typedef unsigned int u32;
typedef float f32x4 __attribute__((ext_vector_type(4)));
typedef short bf16x8 __attribute__((ext_vector_type(8)));
typedef unsigned short u16x4 __attribute__((ext_vector_type(4)));
typedef unsigned int u32x2 __attribute__((ext_vector_type(2)));
typedef unsigned int u32x4 __attribute__((ext_vector_type(4)));

#define BT 2048            // B*T
#define DMODEL 2048
#define HV 32
#define DK 128
#define KEYDIM 2048
#define VALDIM 4096
#define QKVZ_N 12288
#define CONVC 8192         // q,k,v channels
#define INTER 8192

__device__ __forceinline__ float bf2f(u16 v) {
  u32 u = ((u32)v) << 16;
  return __builtin_bit_cast(float, u);
}
__device__ __forceinline__ u16 f2bf(float f) {
  u32 u = __builtin_bit_cast(u32, f);
  u32 r = (u + 0x7fffu + ((u >> 16) & 1u)) >> 16;
  return (u16)r;
}
__device__ __forceinline__ u32 pack2(float a, float b) {
  return (u32)f2bf(a) | ((u32)f2bf(b) << 16);
}
__device__ __forceinline__ float siluf(float x) {
  return x / (1.f + expf(-x));
}

// -------- weight convert+transpose: W[K,N] f32 (row stride ldw) -> Wt[N,K] bf16
__global__ __launch_bounds__(256) void convert_transpose(
    const float* __restrict__ W, int ldw, u16* __restrict__ Wt, int K, int N) {
  __shared__ float tile[32][33];
  int n0 = blockIdx.x * 32, k0 = blockIdx.y * 32;
  int tx = threadIdx.x & 31, ty = threadIdx.x >> 5;  // ty 0..7
#pragma unroll
  for (int i = 0; i < 4; ++i) {
    int kk = ty + i * 8;
    tile[kk][tx] = W[(size_t)(k0 + kk) * ldw + n0 + tx];
  }
  __syncthreads();
#pragma unroll
  for (int i = 0; i < 4; ++i) {
    int nn = ty + i * 8;
    Wt[(size_t)(n0 + nn) * K + k0 + tx] = f2bf(tile[tx][nn]);
  }
}

// -------- fused residual add + gemma RMSNorm (a+b -> resout f32, norm -> bf16)
__global__ __launch_bounds__(256) void resnorm_kernel(
    const float* __restrict__ a, const float* __restrict__ b,
    const float* __restrict__ w, float* __restrict__ resout,
    u16* __restrict__ hb) {
  int tok = blockIdx.x, t = threadIdx.x;
  const float* ap = a + (size_t)tok * DMODEL + t * 8;
  const float* bp = b + (size_t)tok * DMODEL + t * 8;
  f32x4 x0 = *(const f32x4*)ap + *(const f32x4*)bp;
  f32x4 x1 = *(const f32x4*)(ap + 4) + *(const f32x4*)(bp + 4);
  *(f32x4*)(resout + (size_t)tok * DMODEL + t * 8) = x0;
  *(f32x4*)(resout + (size_t)tok * DMODEL + t * 8 + 4) = x1;
  float ss = 0.f;
#pragma unroll
  for (int j = 0; j < 4; ++j) ss += x0[j] * x0[j] + x1[j] * x1[j];
#pragma unroll
  for (int m = 1; m < 64; m <<= 1) ss += __shfl_xor(ss, m, 64);
  __shared__ float red[4];
  if ((t & 63) == 0) red[t >> 6] = ss;
  __syncthreads();
  ss = red[0] + red[1] + red[2] + red[3];
  float sc = rsqrtf(ss * (1.f / (float)DMODEL) + 1e-6f);
  const float* wp = w + t * 8;
  float y[8];
#pragma unroll
  for (int j = 0; j < 4; ++j) {
    y[j] = x0[j] * sc * (1.f + wp[j]);
    y[4 + j] = x1[j] * sc * (1.f + wp[4 + j]);
  }
  u32x4 st;
  st[0] = pack2(y[0], y[1]);
  st[1] = pack2(y[2], y[3]);
  st[2] = pack2(y[4], y[5]);
  st[3] = pack2(y[6], y[7]);
  *(u32x4*)(hb + (size_t)tok * DMODEL + t * 8) = st;
}

// -------- bf16 MFMA GEMM: C[M,N] = A[M,K]_bf16 * Bt[N,K]^T, OUT: 0=f32 1=bf16
__device__ __forceinline__ void async16(const void* g, void* l) {
  __builtin_amdgcn_global_load_lds(
      (const __attribute__((address_space(1))) u32*)g,
      (__attribute__((address_space(3))) u32*)l, 16, 0, 0);
}

template <int OUT>
__global__ __launch_bounds__(256) void gemm_kernel(
    const u16* __restrict__ A, const u16* __restrict__ Bt, void* __restrict__ Cv,
    int M, int N, int K) {
  __shared__ __align__(16) u16 Al[128 * 32];
  __shared__ __align__(16) u16 Bl[128 * 32];
  int tid = threadIdx.x;
  int w = tid >> 6, l = tid & 63;
  int wr = w >> 1, wc = w & 1;
  int m0 = blockIdx.y * 128, n0 = blockIdx.x * 128;
  int r15 = l & 15, kb = l >> 4;

  f32x4 acc[4][4] = {};

  for (int kt = 0; kt < K; kt += 32) {
#pragma unroll
    for (int c = 0; c < 2; ++c) {
      int gid = w * 128 + c * 64 + l;          // 16B granule id in tile
      int row = gid >> 2;
      int g = (gid & 3) ^ ((row >> 1) & 3);    // pre-swizzled source granule
      async16(A + (size_t)(m0 + row) * K + kt + g * 8, Al + gid * 8);
      async16(Bt + (size_t)(n0 + row) * K + kt + g * 8, Bl + gid * 8);
    }
    __syncthreads();
    bf16x8 aF[4], bF[4];
#pragma unroll
    for (int m = 0; m < 4; ++m) {
      int row = wr * 64 + m * 16 + r15;
      aF[m] = *(const bf16x8*)(Al + row * 32 + (kb ^ ((row >> 1) & 3)) * 8);
    }
#pragma unroll
    for (int n = 0; n < 4; ++n) {
      int row = wc * 64 + n * 16 + r15;
      bF[n] = *(const bf16x8*)(Bl + row * 32 + (kb ^ ((row >> 1) & 3)) * 8);
    }
#pragma unroll
    for (int m = 0; m < 4; ++m)
#pragma unroll
      for (int n = 0; n < 4; ++n)
        acc[m][n] = __builtin_amdgcn_mfma_f32_16x16x32_bf16(aF[m], bF[n],
                                                            acc[m][n], 0, 0, 0);
    __syncthreads();
  }

#pragma unroll
  for (int m = 0; m < 4; ++m)
#pragma unroll
    for (int n = 0; n < 4; ++n) {
      size_t base = (size_t)(m0 + wr * 64 + m * 16 + kb * 4) * N +
                    (n0 + wc * 64 + n * 16 + r15);
#pragma unroll
      for (int r = 0; r < 4; ++r) {
        if (OUT == 0)
          ((float*)Cv)[base + (size_t)r * N] = acc[m][n][r];
        else
          ((u16*)Cv)[base + (size_t)r * N] = f2bf(acc[m][n][r]);
      }
    }
}

// -------- ba = hb(bf16) @ Wba(f32 [2048,64]) --------------------------------
__global__ __launch_bounds__(256) void ba_gemm_kernel(
    const u16* __restrict__ hb, const float* __restrict__ Wba,
    float* __restrict__ ba) {
  int m = blockIdx.x;
  int t = threadIdx.x;
  int n = t & 63, kq = t >> 6;
  const u16* a = hb + (size_t)m * DMODEL + kq * 512;
  const float* wp = Wba + (size_t)kq * 512 * 64 + n;
  float sum = 0.f;
  for (int i = 0; i < 512; ++i)
    sum += bf2f(a[i]) * wp[(size_t)i * 64];
  __shared__ float red[256];
  red[t] = sum;
  __syncthreads();
  if (t < 64)
    ba[(size_t)m * 64 + t] = red[t] + red[t + 64] + red[t + 128] + red[t + 192];
}

// -------- causal depthwise conv (K=4) + SiLU, bf16 in/out -------------------
__global__ __launch_bounds__(256) void conv_silu_kernel(
    const u16* __restrict__ qkvb, const float* __restrict__ conv_w,
    u16* __restrict__ qkv) {
  int gid = blockIdx.x * 256 + threadIdx.x;  // BT * 2048 threads
  int c4 = (gid & 2047) * 4;
  int bt = gid >> 11;
  int b = bt >> 10, tt = bt & 1023;
  f32x4 wv[4];
#pragma unroll
  for (int j = 0; j < 4; ++j) wv[j] = *(const f32x4*)(conv_w + (c4 + j) * 4);
  float acc[4] = {0.f, 0.f, 0.f, 0.f};
#pragma unroll
  for (int i = 0; i < 4; ++i) {
    int ts = tt - 3 + i;
    if (ts >= 0) {
      u16x4 x = *(const u16x4*)(qkvb + (size_t)(b * 1024 + ts) * CONVC + c4);
#pragma unroll
      for (int j = 0; j < 4; ++j) acc[j] += bf2f(x[j]) * wv[j][i];
    }
  }
  u32x2 st;
  st[0] = pack2(siluf(acc[0]), siluf(acc[1]));
  st[1] = pack2(siluf(acc[2]), siluf(acc[3]));
  *(u32x2*)(qkv + (size_t)bt * CONVC + c4) = st;
}

// -------- l2 norm of q,k heads in place (bf16), q also * DK^-0.5 ------------
__global__ __launch_bounds__(256) void l2norm_kernel(u16* __restrict__ qkv) {
  int wid = blockIdx.x * 4 + (threadIdx.x >> 6);
  int l = threadIdx.x & 63;
  int tok = wid >> 5, slot = wid & 31;  // slot<16: q head, else k head
  u16* p = qkv + (size_t)tok * CONVC + slot * 128 + l * 2;
  float x0 = bf2f(p[0]), x1 = bf2f(p[1]);
  float ss = x0 * x0 + x1 * x1;
#pragma unroll
  for (int m = 1; m < 64; m <<= 1) ss += __shfl_xor(ss, m, 64);
  float sc = rsqrtf(ss + 1e-6f);
  if (slot < 16) sc *= 0.08838834764831845f;  // DK^-0.5
  *(u32*)p = pack2(x0 * sc, x1 * sc);
}

// -------- beta = sigmoid(bb); decay = exp(-exp(A_log)*softplus(aa+bias)) ----
__global__ __launch_bounds__(256) void betadecay_kernel(
    const float* __restrict__ ba, const float* __restrict__ A_log,
    const float* __restrict__ dt_bias, float* __restrict__ beta,
    float* __restrict__ decay) {
  int idx = blockIdx.x * 256 + threadIdx.x;  // BT*HV
  int h = idx & 31;
  int tok = idx >> 5;
  float bb = ba[(size_t)tok * 64 + h];
  float aa = ba[(size_t)tok * 64 + 32 + h];
  beta[idx] = 1.f / (1.f + expf(-bb));
  float x = aa + dt_bias[h];
  float sp = (x > 20.f) ? x : log1pf(expf(x));
  decay[idx] = expf(-expf(A_log[h]) * sp);
}

// -------- gated delta rule scan (bf16 q/k/v, f32 state) ---------------------
// grid (4 v-chunks, 64 bh). Wave owns 8 v-cols, 8-lane k-split, s[16]/lane.
__global__ __launch_bounds__(256) void scan_kernel(
    const u16* __restrict__ qkv, const float* __restrict__ beta,
    const float* __restrict__ decay, u16* __restrict__ obf) {
  int w = threadIdx.x >> 6, l = threadIdx.x & 63;
  int vc = blockIdx.x;
  int bh = blockIdx.y;
  int b = bh >> 5, h = bh & 31, hk = h >> 1;
  int col = vc * 32 + w * 8 + (l >> 3);
  int kg = l & 7;

  const u16* qp = qkv + (size_t)b * 1024 * CONVC + hk * 128 + kg * 16;
  const u16* kp = qp + KEYDIM;
  const u16* vp = qkv + (size_t)b * 1024 * CONVC + 2 * KEYDIM + h * 128 + col;
  const float* bp = beta + (size_t)b * 1024 * HV + h;
  const float* dp = decay + (size_t)b * 1024 * HV + h;
  u16* op = obf + (size_t)b * 1024 * VALDIM + h * 128 + col;

  float s[16];
#pragma unroll
  for (int i = 0; i < 16; ++i) s[i] = 0.f;

  for (int t = 0; t < 1024; ++t) {
    bf16x8 k0 = *(const bf16x8*)(kp), k1 = *(const bf16x8*)(kp + 8);
    bf16x8 q0 = *(const bf16x8*)(qp), q1 = *(const bf16x8*)(qp + 8);
    float kv[16], qv[16];
#pragma unroll
    for (int i = 0; i < 8; ++i) {
      kv[i] = bf2f((u16)k0[i]);
      kv[8 + i] = bf2f((u16)k1[i]);
      qv[i] = bf2f((u16)q0[i]);
      qv[8 + i] = bf2f((u16)q1[i]);
    }
    float dec = *dp, bet = *bp, vt = bf2f(*vp);
    float dot = 0.f;
#pragma unroll
    for (int i = 0; i < 16; ++i) {
      s[i] *= dec;
      dot += kv[i] * s[i];
    }
    dot += __shfl_xor(dot, 1, 64);
    dot += __shfl_xor(dot, 2, 64);
    dot += __shfl_xor(dot, 4, 64);
    float delta = (vt - dot) * bet;
    float dot2 = 0.f;
#pragma unroll
    for (int i = 0; i < 16; ++i) {
      s[i] += kv[i] * delta;
      dot2 += qv[i] * s[i];
    }
    dot2 += __shfl_xor(dot2, 1, 64);
    dot2 += __shfl_xor(dot2, 2, 64);
    dot2 += __shfl_xor(dot2, 4, 64);
    if (kg == 0) *op = f2bf(dot2);
    qp += CONVC;
    kp += CONVC;
    vp += CONVC;
    bp += HV;
    dp += HV;
    op += VALDIM;
  }
}

// -------- gate (silu(z)) + per-head RMSNorm, in-place over z ----------------
__global__ __launch_bounds__(256) void gatenorm_kernel(
    const u16* __restrict__ obf, u16* __restrict__ zb,
    const float* __restrict__ norm_w) {
  int wid = blockIdx.x * 4 + (threadIdx.x >> 6);
  int l = threadIdx.x & 63;
  int tok = wid >> 5, h = wid & 31;
  const u16* op = obf + (size_t)tok * VALDIM + h * 128 + l * 2;
  u16* zp = zb + (size_t)tok * VALDIM + h * 128 + l * 2;
  float o0 = bf2f(op[0]), o1 = bf2f(op[1]);
  float z0 = bf2f(zp[0]), z1 = bf2f(zp[1]);
  float g0 = o0 * siluf(z0);
  float g1 = o1 * siluf(z1);
  float ss = g0 * g0 + g1 * g1;
#pragma unroll
  for (int m = 1; m < 64; m <<= 1) ss += __shfl_xor(ss, m, 64);
  float sc = rsqrtf(ss * (1.f / 128.f) + 1e-6f);
  int e = l * 2;
  *(u32*)zp = pack2(g0 * sc * norm_w[e], g1 * sc * norm_w[e + 1]);
}

// -------- m = silu(g) * u -> bf16 (in place over u) -------------------------
__global__ __launch_bounds__(256) void mact_kernel(const u16* __restrict__ g,
                                                   u16* __restrict__ u) {
  size_t i = ((size_t)blockIdx.x * 256 + threadIdx.x) * 8;
  bf16x8 gv = *(const bf16x8*)(g + i);
  bf16x8 uv = *(const bf16x8*)(u + i);
  u32x4 st;
#pragma unroll
  for (int j = 0; j < 4; ++j) {
    float a0 = siluf(bf2f((u16)gv[2 * j])) * bf2f((u16)uv[2 * j]);
    float a1 = siluf(bf2f((u16)gv[2 * j + 1])) * bf2f((u16)uv[2 * j + 1]);
    st[j] = pack2(a0, a1);
  }
  *(u32x4*)(u + i) = st;
}

// -------- diagnostic: encode ws_size into d_out[0] --------------------------
__global__ void diag_kernel(float* out, float val) { out[0] = val; }

extern "C" void kernel_launch(void* const* d_in, const int* in_sizes, int n_in,
                              void* d_out, int out_size, void* d_ws,
                              size_t ws_size, hipStream_t stream) {
  const float* hidden = (const float*)d_in[1];
  const float* residual = (const float*)d_in[2];
  const float* ln_in_w = (const float*)d_in[3];
  const float* ln_post_w = (const float*)d_in[4];
  const float* Wqkvz = (const float*)d_in[5];
  const float* Wba = (const float*)d_in[6];
  const float* conv_w = (const float*)d_in[7];
  const float* A_log = (const float*)d_in[8];
  const float* dt_bias = (const float*)d_in[9];
  const float* norm_w = (const float*)d_in[10];
  const float* Wout = (const float*)d_in[11];
  const float* Wgate = (const float*)d_in[12];
  const float* Wup = (const float*)d_in[13];
  const float* Wdown = (const float*)d_in[14];

  char* ws = (char*)d_ws;
  size_t off = 0;
  auto alloc = [&](size_t n) {
    char* p = ws + off;
    off = (off + n + 255) & ~(size_t)255;
    return p;
  };
  u16* wslot = (u16*)alloc((size_t)INTER * DMODEL * 2);       // 33.55 MB
  u16* hb = (u16*)alloc((size_t)BT * DMODEL * 2);             //  8.39 MB
  u16* qkvb = (u16*)alloc((size_t)BT * CONVC * 2);            // 33.55 MB
  u16* zb = (u16*)alloc((size_t)BT * VALDIM * 2);             // 16.78 MB
  u16* qkvc = (u16*)alloc((size_t)BT * CONVC * 2);            // 33.55 MB
  float* ba = (float*)alloc((size_t)BT * 64 * 4);             //  0.52 MB
  float* betab = (float*)alloc((size_t)BT * HV * 4);          //  0.26 MB
  float* decayb = (float*)alloc((size_t)BT * HV * 4);         //  0.26 MB
  u16* obf = (u16*)alloc((size_t)BT * VALDIM * 2);            // 16.78 MB
  if (off > ws_size) {                                        // ~143.7 MB total
    diag_kernel<<<1, 1, 0, stream>>>((float*)d_out, (float)(ws_size >> 20));
    return;
  }

  float* res1 = (float*)d_out;                        // part1 (dead before out)
  float* attn = (float*)d_out + (size_t)BT * DMODEL;  // part2
  float* res2 = attn;                                 // in-place
  u16* h2b = hb;                                      // hb dead after GEMM1/ba
  u16* gbuf = qkvc;                                   // qkvc dead after scan
  u16* ubuf = qkvb;                                   // qkvb dead after conv
  u16* mbuf = qkvb;                                   // in-place over u
  float* outp = (float*)d_out;                        // final (res1 dead)

  dim3 blk(256);

  // 1. res1 = hidden+residual; hb = rmsnorm(res1)
  resnorm_kernel<<<BT, blk, 0, stream>>>(hidden, residual, ln_in_w, res1, hb);

  // 2. qkv-slice GEMM: qkvb = hb @ Wqkvz[:, :8192]
  convert_transpose<<<dim3(CONVC / 32, DMODEL / 32), blk, 0, stream>>>(
      Wqkvz, QKVZ_N, wslot, DMODEL, CONVC);
  gemm_kernel<1><<<dim3(CONVC / 128, BT / 128), blk, 0, stream>>>(
      hb, wslot, qkvb, BT, CONVC, DMODEL);

  // 3. z-slice GEMM: zb = hb @ Wqkvz[:, 8192:]
  convert_transpose<<<dim3(VALDIM / 32, DMODEL / 32), blk, 0, stream>>>(
      Wqkvz + CONVC, QKVZ_N, wslot, DMODEL, VALDIM);
  gemm_kernel<1><<<dim3(VALDIM / 128, BT / 128), blk, 0, stream>>>(
      hb, wslot, zb, BT, VALDIM, DMODEL);

  // 4. ba = hb @ Wba
  ba_gemm_kernel<<<BT, blk, 0, stream>>>(hb, Wba, ba);

  // 5-7. conv+silu, l2norm(q,k), beta/decay
  conv_silu_kernel<<<BT * 2048 / 256, blk, 0, stream>>>(qkvb, conv_w, qkvc);
  l2norm_kernel<<<BT * 32 / 4, blk, 0, stream>>>(qkvc);
  betadecay_kernel<<<BT * HV / 256, blk, 0, stream>>>(ba, A_log, dt_bias,
                                                      betab, decayb);

  // 8. gated delta rule scan
  scan_kernel<<<dim3(4, 64), blk, 0, stream>>>(qkvc, betab, decayb, obf);

  // 9. gate + per-head RMSNorm (in place over zb)
  gatenorm_kernel<<<BT * HV / 4, blk, 0, stream>>>(obf, zb, norm_w);

  // 10. attn = og @ Wout  (f32, into d_out part2)
  convert_transpose<<<dim3(DMODEL / 32, VALDIM / 32), blk, 0, stream>>>(
      Wout, DMODEL, wslot, VALDIM, DMODEL);
  gemm_kernel<0><<<dim3(DMODEL / 128, BT / 128), blk, 0, stream>>>(
      zb, wslot, attn, BT, DMODEL, VALDIM);

  // 11. res2 = attn + res1 (in place, part2); h2b = rmsnorm(res2)
  resnorm_kernel<<<BT, blk, 0, stream>>>(attn, res1, ln_post_w, res2, h2b);

  // 12-13. gate & up GEMMs (bf16 outs)
  convert_transpose<<<dim3(INTER / 32, DMODEL / 32), blk, 0, stream>>>(
      Wgate, INTER, wslot, DMODEL, INTER);
  gemm_kernel<1><<<dim3(INTER / 128, BT / 128), blk, 0, stream>>>(
      h2b, wslot, gbuf, BT, INTER, DMODEL);
  convert_transpose<<<dim3(INTER / 32, DMODEL / 32), blk, 0, stream>>>(
      Wup, INTER, wslot, DMODEL, INTER);
  gemm_kernel<1><<<dim3(INTER / 128, BT / 128), blk, 0, stream>>>(
      h2b, wslot, ubuf, BT, INTER, DMODEL);

  // 14. m = silu(g)*u (in place over u)
  mact_kernel<<<BT * INTER / 8 / 256, blk, 0, stream>>>(gbuf, ubuf);

  // 15. out = m @ Wdown (f32, d_out part1)
  convert_transpose<<<dim3(DMODEL / 32, INTER / 32), blk, 0, stream>>>(
      Wdown, DMODEL, wslot, INTER, DMODEL);
  gemm_kernel<0><<<dim3(DMODEL / 128, BT / 128), blk, 0, stream>>>(
      mbuf, wslot, outp, BT, DMODEL, INTER);
}

// Round 3
// 1613.211 us; speedup vs baseline: 1.0043x; 1.0043x over previous
//
#include <hip/hip_runtime.h>
#include <hip/hip_bf16.h>

typedef unsigned short u16;
typedef unsigned int u32;
typedef float f32x4 __attribute__((ext_vector_type(4)));
typedef short bf16x8 __attribute__((ext_vector_type(8)));
typedef unsigned short u16x4 __attribute__((ext_vector_type(4)));
typedef unsigned int u32x2 __attribute__((ext_vector_type(2)));
typedef unsigned int u32x4 __attribute__((ext_vector_type(4)));

#define BT 2048            // B*T
#define DMODEL 2048
#define HV 32
#define DK 128
#define KEYDIM 2048
#define VALDIM 4096
#define QKVZ_N 12288
#define CONVC 8192         // q,k,v channels
#define INTER 8192

__device__ __forceinline__ float bf2f(u16 v) {
  u32 u = ((u32)v) << 16;
  return __builtin_bit_cast(float, u);
}
__device__ __forceinline__ u16 f2bf(float f) {
  u32 u = __builtin_bit_cast(u32, f);
  u32 r = (u + 0x7fffu + ((u >> 16) & 1u)) >> 16;
  return (u16)r;
}
__device__ __forceinline__ u32 pack2(float a, float b) {
  return (u32)f2bf(a) | ((u32)f2bf(b) << 16);
}
__device__ __forceinline__ float siluf(float x) {
  return x / (1.f + expf(-x));
}

// -------- weight convert+transpose: W[K,N] f32 (row stride ldw) -> Wt[N,K] bf16
__global__ __launch_bounds__(256) void convert_transpose(
    const float* __restrict__ W, int ldw, u16* __restrict__ Wt, int K, int N) {
  __shared__ float tile[32][33];
  int n0 = blockIdx.x * 32, k0 = blockIdx.y * 32;
  int tx = threadIdx.x & 31, ty = threadIdx.x >> 5;  // ty 0..7
#pragma unroll
  for (int i = 0; i < 4; ++i) {
    int kk = ty + i * 8;
    tile[kk][tx] = W[(size_t)(k0 + kk) * ldw + n0 + tx];
  }
  __syncthreads();
#pragma unroll
  for (int i = 0; i < 4; ++i) {
    int nn = ty + i * 8;
    Wt[(size_t)(n0 + nn) * K + k0 + tx] = f2bf(tile[tx][nn]);
  }
}

// -------- fused residual add + gemma RMSNorm (a+b -> resout f32, norm -> bf16)
__global__ __launch_bounds__(256) void resnorm_kernel(
    const float* __restrict__ a, const float* __restrict__ b,
    const float* __restrict__ w, float* __restrict__ resout,
    u16* __restrict__ hb) {
  int tok = blockIdx.x, t = threadIdx.x;
  const float* ap = a + (size_t)tok * DMODEL + t * 8;
  const float* bp = b + (size_t)tok * DMODEL + t * 8;
  f32x4 x0 = *(const f32x4*)ap + *(const f32x4*)bp;
  f32x4 x1 = *(const f32x4*)(ap + 4) + *(const f32x4*)(bp + 4);
  *(f32x4*)(resout + (size_t)tok * DMODEL + t * 8) = x0;
  *(f32x4*)(resout + (size_t)tok * DMODEL + t * 8 + 4) = x1;
  float ss = 0.f;
#pragma unroll
  for (int j = 0; j < 4; ++j) ss += x0[j] * x0[j] + x1[j] * x1[j];
#pragma unroll
  for (int m = 1; m < 64; m <<= 1) ss += __shfl_xor(ss, m, 64);
  __shared__ float red[4];
  if ((t & 63) == 0) red[t >> 6] = ss;
  __syncthreads();
  ss = red[0] + red[1] + red[2] + red[3];
  float sc = rsqrtf(ss * (1.f / (float)DMODEL) + 1e-6f);
  const float* wp = w + t * 8;
  float y[8];
#pragma unroll
  for (int j = 0; j < 4; ++j) {
    y[j] = x0[j] * sc * (1.f + wp[j]);
    y[4 + j] = x1[j] * sc * (1.f + wp[4 + j]);
  }
  u32x4 st;
  st[0] = pack2(y[0], y[1]);
  st[1] = pack2(y[2], y[3]);
  st[2] = pack2(y[4], y[5]);
  st[3] = pack2(y[6], y[7]);
  *(u32x4*)(hb + (size_t)tok * DMODEL + t * 8) = st;
}

// -------- bf16 MFMA GEMM: C[M,N] = A[M,K]_bf16 * Bt[N,K]^T, OUT: 0=f32 1=bf16
__device__ __forceinline__ void async16(const void* g, void* l) {
  __builtin_amdgcn_global_load_lds(
      (const __attribute__((address_space(1))) u32*)g,
      (__attribute__((address_space(3))) u32*)l, 16, 0, 0);
}

template <int OUT>
__global__ __launch_bounds__(256) void gemm_kernel(
    const u16* __restrict__ A, const u16* __restrict__ Bt, void* __restrict__ Cv,
    int M, int N, int K) {
  __shared__ __align__(16) u16 Al[128 * 32];
  __shared__ __align__(16) u16 Bl[128 * 32];
  int tid = threadIdx.x;
  int w = tid >> 6, l = tid & 63;
  int wr = w >> 1, wc = w & 1;
  int m0 = blockIdx.y * 128, n0 = blockIdx.x * 128;
  int r15 = l & 15, kb = l >> 4;

  f32x4 acc[4][4] = {};

  for (int kt = 0; kt < K; kt += 32) {
#pragma unroll
    for (int c = 0; c < 2; ++c) {
      int gid = w * 128 + c * 64 + l;          // 16B granule id in tile
      int row = gid >> 2;
      int g = (gid & 3) ^ ((row >> 1) & 3);    // pre-swizzled source granule
      async16(A + (size_t)(m0 + row) * K + kt + g * 8, Al + gid * 8);
      async16(Bt + (size_t)(n0 + row) * K + kt + g * 8, Bl + gid * 8);
    }
    __syncthreads();
    bf16x8 aF[4], bF[4];
#pragma unroll
    for (int m = 0; m < 4; ++m) {
      int row = wr * 64 + m * 16 + r15;
      aF[m] = *(const bf16x8*)(Al + row * 32 + (kb ^ ((row >> 1) & 3)) * 8);
    }
#pragma unroll
    for (int n = 0; n < 4; ++n) {
      int row = wc * 64 + n * 16 + r15;
      bF[n] = *(const bf16x8*)(Bl + row * 32 + (kb ^ ((row >> 1) & 3)) * 8);
    }
#pragma unroll
    for (int m = 0; m < 4; ++m)
#pragma unroll
      for (int n = 0; n < 4; ++n)
        acc[m][n] = __builtin_amdgcn_mfma_f32_16x16x32_bf16(aF[m], bF[n],
                                                            acc[m][n], 0, 0, 0);
    __syncthreads();
  }

#pragma unroll
  for (int m = 0; m < 4; ++m)
#pragma unroll
    for (int n = 0; n < 4; ++n) {
      size_t base = (size_t)(m0 + wr * 64 + m * 16 + kb * 4) * N +
                    (n0 + wc * 64 + n * 16 + r15);
#pragma unroll
      for (int r = 0; r < 4; ++r) {
        if (OUT == 0)
          ((float*)Cv)[base + (size_t)r * N] = acc[m][n][r];
        else
          ((u16*)Cv)[base + (size_t)r * N] = f2bf(acc[m][n][r]);
      }
    }
}

// -------- ba = hb(bf16) @ Wba(f32 [2048,64]) --------------------------------
__global__ __launch_bounds__(256) void ba_gemm_kernel(
    const u16* __restrict__ hb, const float* __restrict__ Wba,
    float* __restrict__ ba) {
  int m = blockIdx.x;
  int t = threadIdx.x;
  int n = t & 63, kq = t >> 6;
  const u16* a = hb + (size_t)m * DMODEL + kq * 512;
  const float* wp = Wba + (size_t)kq * 512 * 64 + n;
  float sum = 0.f;
  for (int i = 0; i < 512; ++i)
    sum += bf2f(a[i]) * wp[(size_t)i * 64];
  __shared__ float red[256];
  red[t] = sum;
  __syncthreads();
  if (t < 64)
    ba[(size_t)m * 64 + t] = red[t] + red[t + 64] + red[t + 128] + red[t + 192];
}

// -------- causal depthwise conv (K=4) + SiLU, bf16 in/out -------------------
__global__ __launch_bounds__(256) void conv_silu_kernel(
    const u16* __restrict__ qkvb, const float* __restrict__ conv_w,
    u16* __restrict__ qkv) {
  int gid = blockIdx.x * 256 + threadIdx.x;  // BT * 2048 threads
  int c4 = (gid & 2047) * 4;
  int bt = gid >> 11;
  int b = bt >> 10, tt = bt & 1023;
  f32x4 wv[4];
#pragma unroll
  for (int j = 0; j < 4; ++j) wv[j] = *(const f32x4*)(conv_w + (c4 + j) * 4);
  float acc[4] = {0.f, 0.f, 0.f, 0.f};
#pragma unroll
  for (int i = 0; i < 4; ++i) {
    int ts = tt - 3 + i;
    if (ts >= 0) {
      u16x4 x = *(const u16x4*)(qkvb + (size_t)(b * 1024 + ts) * CONVC + c4);
#pragma unroll
      for (int j = 0; j < 4; ++j) acc[j] += bf2f(x[j]) * wv[j][i];
    }
  }
  u32x2 st;
  st[0] = pack2(siluf(acc[0]), siluf(acc[1]));
  st[1] = pack2(siluf(acc[2]), siluf(acc[3]));
  *(u32x2*)(qkv + (size_t)bt * CONVC + c4) = st;
}

// -------- l2 norm of q,k heads in place (bf16), q also * DK^-0.5 ------------
__global__ __launch_bounds__(256) void l2norm_kernel(u16* __restrict__ qkv) {
  int wid = blockIdx.x * 4 + (threadIdx.x >> 6);
  int l = threadIdx.x & 63;
  int tok = wid >> 5, slot = wid & 31;  // slot<16: q head, else k head
  u16* p = qkv + (size_t)tok * CONVC + slot * 128 + l * 2;
  float x0 = bf2f(p[0]), x1 = bf2f(p[1]);
  float ss = x0 * x0 + x1 * x1;
#pragma unroll
  for (int m = 1; m < 64; m <<= 1) ss += __shfl_xor(ss, m, 64);
  float sc = rsqrtf(ss + 1e-6f);
  if (slot < 16) sc *= 0.08838834764831845f;  // DK^-0.5
  *(u32*)p = pack2(x0 * sc, x1 * sc);
}

// -------- beta = sigmoid(bb); decay = exp(-exp(A_log)*softplus(aa+bias)) ----
__global__ __launch_bounds__(256) void betadecay_kernel(
    const float* __restrict__ ba, const float* __restrict__ A_log,
    const float* __restrict__ dt_bias, float* __restrict__ beta,
    float* __restrict__ decay) {
  int idx = blockIdx.x * 256 + threadIdx.x;  // BT*HV
  int h = idx & 31;
  int tok = idx >> 5;
  float bb = ba[(size_t)tok * 64 + h];
  float aa = ba[(size_t)tok * 64 + 32 + h];
  beta[idx] = 1.f / (1.f + expf(-bb));
  float x = aa + dt_bias[h];
  float sp = (x > 20.f) ? x : log1pf(expf(x));
  decay[idx] = expf(-expf(A_log[h]) * sp);
}

// -------- gated delta rule scan (bf16 q/k/v, f32 state) ---------------------
// grid (8 vc, 64 bh), block 256 = 4 waves. Wave: 4 v-cols x 16-lane k-split,
// s[8]/lane. Register double-buffer prefetch of t+1 inputs; tree-reduced dots.
__global__ __launch_bounds__(256) void scan_kernel(
    const u16* __restrict__ qkv, const float* __restrict__ beta,
    const float* __restrict__ decay, u16* __restrict__ obf) {
  int w = threadIdx.x >> 6, l = threadIdx.x & 63;
  int vc = blockIdx.x;
  int bh = blockIdx.y;
  int b = bh >> 5, h = bh & 31, hk = h >> 1;
  int col = vc * 16 + w * 4 + (l >> 4);
  int kg = l & 15;

  const u16* qp = qkv + (size_t)b * 1024 * CONVC + hk * 128 + kg * 8;
  const u16* kp = qp + KEYDIM;
  const u16* vp = qkv + (size_t)b * 1024 * CONVC + 2 * KEYDIM + h * 128 + col;
  const float* bp = beta + (size_t)b * 1024 * HV + h;
  const float* dp = decay + (size_t)b * 1024 * HV + h;
  u16* op = obf + (size_t)b * 1024 * VALDIM + h * 128 + col;

  float s[8];
#pragma unroll
  for (int i = 0; i < 8; ++i) s[i] = 0.f;

  // prefetch t = 0
  bf16x8 kn = *(const bf16x8*)kp;
  bf16x8 qn = *(const bf16x8*)qp;
  float vn = bf2f(*vp), bn = *bp, dn = *dp;

  for (int t = 0; t < 1024; ++t) {
    bf16x8 kc = kn, qc = qn;
    float vt = vn, bet = bn, dec = dn;
    if (t < 1023) {  // issue t+1 loads before compute; latency hides under it
      qp += CONVC; kp += CONVC; vp += CONVC; bp += HV; dp += HV;
      kn = *(const bf16x8*)kp;
      qn = *(const bf16x8*)qp;
      vn = bf2f(*vp);
      bn = *bp;
      dn = *dp;
    }
    float kv[8], qv[8];
#pragma unroll
    for (int i = 0; i < 8; ++i) {
      kv[i] = bf2f((u16)kc[i]);
      qv[i] = bf2f((u16)qc[i]);
    }
#pragma unroll
    for (int i = 0; i < 8; ++i) s[i] *= dec;
    float d0 = fmaf(kv[1], s[1], kv[0] * s[0]);
    float d1 = fmaf(kv[3], s[3], kv[2] * s[2]);
    float d2 = fmaf(kv[5], s[5], kv[4] * s[4]);
    float d3 = fmaf(kv[7], s[7], kv[6] * s[6]);
    float dot = (d0 + d1) + (d2 + d3);
    dot += __shfl_xor(dot, 1, 64);
    dot += __shfl_xor(dot, 2, 64);
    dot += __shfl_xor(dot, 4, 64);
    dot += __shfl_xor(dot, 8, 64);
    float delta = (vt - dot) * bet;
#pragma unroll
    for (int i = 0; i < 8; ++i) s[i] = fmaf(kv[i], delta, s[i]);
    float e0 = fmaf(qv[1], s[1], qv[0] * s[0]);
    float e1 = fmaf(qv[3], s[3], qv[2] * s[2]);
    float e2 = fmaf(qv[5], s[5], qv[4] * s[4]);
    float e3 = fmaf(qv[7], s[7], qv[6] * s[6]);
    float dot2 = (e0 + e1) + (e2 + e3);
    dot2 += __shfl_xor(dot2, 1, 64);
    dot2 += __shfl_xor(dot2, 2, 64);
    dot2 += __shfl_xor(dot2, 4, 64);
    dot2 += __shfl_xor(dot2, 8, 64);
    if (kg == 0) *op = f2bf(dot2);
    op += VALDIM;
  }
}

// -------- gate (silu(z)) + per-head RMSNorm, in-place over z ----------------
__global__ __launch_bounds__(256) void gatenorm_kernel(
    const u16* __restrict__ obf, u16* __restrict__ zb,
    const float* __restrict__ norm_w) {
  int wid = blockIdx.x * 4 + (threadIdx.x >> 6);
  int l = threadIdx.x & 63;
  int tok = wid >> 5, h = wid & 31;
  const u16* op = obf + (size_t)tok * VALDIM + h * 128 + l * 2;
  u16* zp = zb + (size_t)tok * VALDIM + h * 128 + l * 2;
  float o0 = bf2f(op[0]), o1 = bf2f(op[1]);
  float z0 = bf2f(zp[0]), z1 = bf2f(zp[1]);
  float g0 = o0 * siluf(z0);
  float g1 = o1 * siluf(z1);
  float ss = g0 * g0 + g1 * g1;
#pragma unroll
  for (int m = 1; m < 64; m <<= 1) ss += __shfl_xor(ss, m, 64);
  float sc = rsqrtf(ss * (1.f / 128.f) + 1e-6f);
  int e = l * 2;
  *(u32*)zp = pack2(g0 * sc * norm_w[e], g1 * sc * norm_w[e + 1]);
}

// -------- m = silu(g) * u -> bf16 (in place over u) -------------------------
__global__ __launch_bounds__(256) void mact_kernel(const u16* __restrict__ g,
                                                   u16* __restrict__ u) {
  size_t i = ((size_t)blockIdx.x * 256 + threadIdx.x) * 8;
  bf16x8 gv = *(const bf16x8*)(g + i);
  bf16x8 uv = *(const bf16x8*)(u + i);
  u32x4 st;
#pragma unroll
  for (int j = 0; j < 4; ++j) {
    float a0 = siluf(bf2f((u16)gv[2 * j])) * bf2f((u16)uv[2 * j]);
    float a1 = siluf(bf2f((u16)gv[2 * j + 1])) * bf2f((u16)uv[2 * j + 1]);
    st[j] = pack2(a0, a1);
  }
  *(u32x4*)(u + i) = st;
}

// -------- diagnostic: encode ws_size into d_out[0] --------------------------
__global__ void diag_kernel(float* out, float val) { out[0] = val; }

extern "C" void kernel_launch(void* const* d_in, const int* in_sizes, int n_in,
                              void* d_out, int out_size, void* d_ws,
                              size_t ws_size, hipStream_t stream) {
  const float* hidden = (const float*)d_in[1];
  const float* residual = (const float*)d_in[2];
  const float* ln_in_w = (const float*)d_in[3];
  const float* ln_post_w = (const float*)d_in[4];
  const float* Wqkvz = (const float*)d_in[5];
  const float* Wba = (const float*)d_in[6];
  const float* conv_w = (const float*)d_in[7];
  const float* A_log = (const float*)d_in[8];
  const float* dt_bias = (const float*)d_in[9];
  const float* norm_w = (const float*)d_in[10];
  const float* Wout = (const float*)d_in[11];
  const float* Wgate = (const float*)d_in[12];
  const float* Wup = (const float*)d_in[13];
  const float* Wdown = (const float*)d_in[14];

  char* ws = (char*)d_ws;
  size_t off = 0;
  auto alloc = [&](size_t n) {
    char* p = ws + off;
    off = (off + n + 255) & ~(size_t)255;
    return p;
  };
  u16* wslot = (u16*)alloc((size_t)INTER * DMODEL * 2);       // 33.55 MB
  u16* hb = (u16*)alloc((size_t)BT * DMODEL * 2);             //  8.39 MB
  u16* qkvb = (u16*)alloc((size_t)BT * CONVC * 2);            // 33.55 MB
  u16* zb = (u16*)alloc((size_t)BT * VALDIM * 2);             // 16.78 MB
  u16* qkvc = (u16*)alloc((size_t)BT * CONVC * 2);            // 33.55 MB
  float* ba = (float*)alloc((size_t)BT * 64 * 4);             //  0.52 MB
  float* betab = (float*)alloc((size_t)BT * HV * 4);          //  0.26 MB
  float* decayb = (float*)alloc((size_t)BT * HV * 4);         //  0.26 MB
  u16* obf = (u16*)alloc((size_t)BT * VALDIM * 2);            // 16.78 MB
  if (off > ws_size) {                                        // ~143.7 MB total
    diag_kernel<<<1, 1, 0, stream>>>((float*)d_out, (float)(ws_size >> 20));
    return;
  }

  float* res1 = (float*)d_out;                        // part1 (dead before out)
  float* attn = (float*)d_out + (size_t)BT * DMODEL;  // part2
  float* res2 = attn;                                 // in-place
  u16* h2b = hb;                                      // hb dead after GEMM1/ba
  u16* gbuf = qkvc;                                   // qkvc dead after scan
  u16* ubuf = qkvb;                                   // qkvb dead after conv
  u16* mbuf = qkvb;                                   // in-place over u
  float* outp = (float*)d_out;                        // final (res1 dead)

  dim3 blk(256);

  // 1. res1 = hidden+residual; hb = rmsnorm(res1)
  resnorm_kernel<<<BT, blk, 0, stream>>>(hidden, residual, ln_in_w, res1, hb);

  // 2. qkv-slice GEMM: qkvb = hb @ Wqkvz[:, :8192]
  convert_transpose<<<dim3(CONVC / 32, DMODEL / 32), blk, 0, stream>>>(
      Wqkvz, QKVZ_N, wslot, DMODEL, CONVC);
  gemm_kernel<1><<<dim3(CONVC / 128, BT / 128), blk, 0, stream>>>(
      hb, wslot, qkvb, BT, CONVC, DMODEL);

  // 3. z-slice GEMM: zb = hb @ Wqkvz[:, 8192:]
  convert_transpose<<<dim3(VALDIM / 32, DMODEL / 32), blk, 0, stream>>>(
      Wqkvz + CONVC, QKVZ_N, wslot, DMODEL, VALDIM);
  gemm_kernel<1><<<dim3(VALDIM / 128, BT / 128), blk, 0, stream>>>(
      hb, wslot, zb, BT, VALDIM, DMODEL);

  // 4. ba = hb @ Wba
  ba_gemm_kernel<<<BT, blk, 0, stream>>>(hb, Wba, ba);

  // 5-7. conv+silu, l2norm(q,k), beta/decay
  conv_silu_kernel<<<BT * 2048 / 256, blk, 0, stream>>>(qkvb, conv_w, qkvc);
  l2norm_kernel<<<BT * 32 / 4, blk, 0, stream>>>(qkvc);
  betadecay_kernel<<<BT * HV / 256, blk, 0, stream>>>(ba, A_log, dt_bias,
                                                      betab, decayb);

  // 8. gated delta rule scan
  scan_kernel<<<dim3(8, 64), blk, 0, stream>>>(qkvc, betab, decayb, obf);

  // 9. gate + per-head RMSNorm (in place over zb)
  gatenorm_kernel<<<BT * HV / 4, blk, 0, stream>>>(obf, zb, norm_w);

  // 10. attn = og @ Wout  (f32, into d_out part2)
  convert_transpose<<<dim3(DMODEL / 32, VALDIM / 32), blk, 0, stream>>>(
      Wout, DMODEL, wslot, VALDIM, DMODEL);
  gemm_kernel<0><<<dim3(DMODEL / 128, BT / 128), blk, 0, stream>>>(
      zb, wslot, attn, BT, DMODEL, VALDIM);

  // 11. res2 = attn + res1 (in place, part2); h2b = rmsnorm(res2)
  resnorm_kernel<<<BT, blk, 0, stream>>>(attn, res1, ln_post_w, res2, h2b);

  // 12-13. gate & up GEMMs (bf16 outs)
  convert_transpose<<<dim3(INTER / 32, DMODEL / 32), blk, 0, stream>>>(
      Wgate, INTER, wslot, DMODEL, INTER);
  gemm_kernel<1><<<dim3(INTER / 128, BT / 128), blk, 0, stream>>>(
      h2b, wslot, gbuf, BT, INTER, DMODEL);
  convert_transpose<<<dim3(INTER / 32, DMODEL / 32), blk, 0, stream>>>(
      Wup, INTER, wslot, DMODEL, INTER);
  gemm_kernel<1><<<dim3(INTER / 128, BT / 128), blk, 0, stream>>>(
      h2b, wslot, ubuf, BT, INTER, DMODEL);

  // 14. m = silu(g)*u (in place over u)
  mact_kernel<<<BT * INTER / 8 / 256, blk, 0, stream>>>(gbuf, ubuf);

  // 15. out = m @ Wdown (f32, d_out part1)
  convert_transpose<<<dim3(DMODEL / 32, INTER / 32), blk, 0, stream>>>(
      Wdown, DMODEL, wslot, INTER, DMODEL);
  gemm_kernel<0><<<dim3(DMODEL / 128, BT / 128), blk, 0, stream>>>(
      mbuf, wslot, outp, BT, DMODEL, INTER);
}

// Round 4
// 1364.322 us; speedup vs baseline: 1.1875x; 1.1824x over previous
//
#include <hip/hip_runtime.h>
#include <hip/hip_bf16.h>

typedef unsigned short u16;
typedef unsigned int u32;
typedef float f32x4 __attribute__((ext_vector_type(4)));
typedef short bf16x8 __attribute__((ext_vector_type(8)));
typedef unsigned short u16x4 __attribute__((ext_vector_type(4)));
typedef unsigned int u32x2 __attribute__((ext_vector_type(2)));
typedef unsigned int u32x4 __attribute__((ext_vector_type(4)));

#define BT 2048            // B*T
#define DMODEL 2048
#define HV 32
#define DK 128
#define KEYDIM 2048
#define VALDIM 4096
#define QKVZ_N 12288
#define CONVC 8192         // q,k,v channels
#define INTER 8192

__device__ __forceinline__ float bf2f(u16 v) {
  u32 u = ((u32)v) << 16;
  return __builtin_bit_cast(float, u);
}
__device__ __forceinline__ u16 f2bf(float f) {
  u32 u = __builtin_bit_cast(u32, f);
  u32 r = (u + 0x7fffu + ((u >> 16) & 1u)) >> 16;
  return (u16)r;
}
__device__ __forceinline__ u32 pack2(float a, float b) {
  return (u32)f2bf(a) | ((u32)f2bf(b) << 16);
}
__device__ __forceinline__ float siluf(float x) {
  return x / (1.f + expf(-x));
}

// -------- weight convert+transpose: W[K,N] f32 (row stride ldw) -> Wt[N,K] bf16
__global__ __launch_bounds__(256) void convert_transpose(
    const float* __restrict__ W, int ldw, u16* __restrict__ Wt, int K, int N) {
  __shared__ float tile[32][33];
  int n0 = blockIdx.x * 32, k0 = blockIdx.y * 32;
  int tx = threadIdx.x & 31, ty = threadIdx.x >> 5;  // ty 0..7
#pragma unroll
  for (int i = 0; i < 4; ++i) {
    int kk = ty + i * 8;
    tile[kk][tx] = W[(size_t)(k0 + kk) * ldw + n0 + tx];
  }
  __syncthreads();
#pragma unroll
  for (int i = 0; i < 4; ++i) {
    int nn = ty + i * 8;
    Wt[(size_t)(n0 + nn) * K + k0 + tx] = f2bf(tile[tx][nn]);
  }
}

// -------- fused residual add + gemma RMSNorm (a+b -> resout f32, norm -> bf16)
__global__ __launch_bounds__(256) void resnorm_kernel(
    const float* __restrict__ a, const float* __restrict__ b,
    const float* __restrict__ w, float* __restrict__ resout,
    u16* __restrict__ hb) {
  int tok = blockIdx.x, t = threadIdx.x;
  const float* ap = a + (size_t)tok * DMODEL + t * 8;
  const float* bp = b + (size_t)tok * DMODEL + t * 8;
  f32x4 x0 = *(const f32x4*)ap + *(const f32x4*)bp;
  f32x4 x1 = *(const f32x4*)(ap + 4) + *(const f32x4*)(bp + 4);
  *(f32x4*)(resout + (size_t)tok * DMODEL + t * 8) = x0;
  *(f32x4*)(resout + (size_t)tok * DMODEL + t * 8 + 4) = x1;
  float ss = 0.f;
#pragma unroll
  for (int j = 0; j < 4; ++j) ss += x0[j] * x0[j] + x1[j] * x1[j];
#pragma unroll
  for (int m = 1; m < 64; m <<= 1) ss += __shfl_xor(ss, m, 64);
  __shared__ float red[4];
  if ((t & 63) == 0) red[t >> 6] = ss;
  __syncthreads();
  ss = red[0] + red[1] + red[2] + red[3];
  float sc = rsqrtf(ss * (1.f / (float)DMODEL) + 1e-6f);
  const float* wp = w + t * 8;
  float y[8];
#pragma unroll
  for (int j = 0; j < 4; ++j) {
    y[j] = x0[j] * sc * (1.f + wp[j]);
    y[4 + j] = x1[j] * sc * (1.f + wp[4 + j]);
  }
  u32x4 st;
  st[0] = pack2(y[0], y[1]);
  st[1] = pack2(y[2], y[3]);
  st[2] = pack2(y[4], y[5]);
  st[3] = pack2(y[6], y[7]);
  *(u32x4*)(hb + (size_t)tok * DMODEL + t * 8) = st;
}

// -------- bf16 MFMA GEMM: C[M,N] = A[M,K]_bf16 * Bt[N,K]^T, OUT: 0=f32 1=bf16
__device__ __forceinline__ void async16(const void* g, void* l) {
  __builtin_amdgcn_global_load_lds(
      (const __attribute__((address_space(1))) u32*)g,
      (__attribute__((address_space(3))) u32*)l, 16, 0, 0);
}

template <int OUT>
__global__ __launch_bounds__(256) void gemm_kernel(
    const u16* __restrict__ A, const u16* __restrict__ Bt, void* __restrict__ Cv,
    int M, int N, int K) {
  __shared__ __align__(16) u16 Al[128 * 32];
  __shared__ __align__(16) u16 Bl[128 * 32];
  int tid = threadIdx.x;
  int w = tid >> 6, l = tid & 63;
  int wr = w >> 1, wc = w & 1;
  int m0 = blockIdx.y * 128, n0 = blockIdx.x * 128;
  int r15 = l & 15, kb = l >> 4;

  f32x4 acc[4][4] = {};

  for (int kt = 0; kt < K; kt += 32) {
#pragma unroll
    for (int c = 0; c < 2; ++c) {
      int gid = w * 128 + c * 64 + l;          // 16B granule id in tile
      int row = gid >> 2;
      int g = (gid & 3) ^ ((row >> 1) & 3);    // pre-swizzled source granule
      async16(A + (size_t)(m0 + row) * K + kt + g * 8, Al + gid * 8);
      async16(Bt + (size_t)(n0 + row) * K + kt + g * 8, Bl + gid * 8);
    }
    __syncthreads();
    bf16x8 aF[4], bF[4];
#pragma unroll
    for (int m = 0; m < 4; ++m) {
      int row = wr * 64 + m * 16 + r15;
      aF[m] = *(const bf16x8*)(Al + row * 32 + (kb ^ ((row >> 1) & 3)) * 8);
    }
#pragma unroll
    for (int n = 0; n < 4; ++n) {
      int row = wc * 64 + n * 16 + r15;
      bF[n] = *(const bf16x8*)(Bl + row * 32 + (kb ^ ((row >> 1) & 3)) * 8);
    }
#pragma unroll
    for (int m = 0; m < 4; ++m)
#pragma unroll
      for (int n = 0; n < 4; ++n)
        acc[m][n] = __builtin_amdgcn_mfma_f32_16x16x32_bf16(aF[m], bF[n],
                                                            acc[m][n], 0, 0, 0);
    __syncthreads();
  }

#pragma unroll
  for (int m = 0; m < 4; ++m)
#pragma unroll
    for (int n = 0; n < 4; ++n) {
      size_t base = (size_t)(m0 + wr * 64 + m * 16 + kb * 4) * N +
                    (n0 + wc * 64 + n * 16 + r15);
#pragma unroll
      for (int r = 0; r < 4; ++r) {
        if (OUT == 0)
          ((float*)Cv)[base + (size_t)r * N] = acc[m][n][r];
        else
          ((u16*)Cv)[base + (size_t)r * N] = f2bf(acc[m][n][r]);
      }
    }
}

// -------- ba = hb(bf16) @ Wba(f32 [2048,64]) --------------------------------
__global__ __launch_bounds__(256) void ba_gemm_kernel(
    const u16* __restrict__ hb, const float* __restrict__ Wba,
    float* __restrict__ ba) {
  int m = blockIdx.x;
  int t = threadIdx.x;
  int n = t & 63, kq = t >> 6;
  const u16* a = hb + (size_t)m * DMODEL + kq * 512;
  const float* wp = Wba + (size_t)kq * 512 * 64 + n;
  float sum = 0.f;
  for (int i = 0; i < 512; ++i)
    sum += bf2f(a[i]) * wp[(size_t)i * 64];
  __shared__ float red[256];
  red[t] = sum;
  __syncthreads();
  if (t < 64)
    ba[(size_t)m * 64 + t] = red[t] + red[t + 64] + red[t + 128] + red[t + 192];
}

// -------- causal depthwise conv (K=4) + SiLU, bf16 in/out -------------------
__global__ __launch_bounds__(256) void conv_silu_kernel(
    const u16* __restrict__ qkvb, const float* __restrict__ conv_w,
    u16* __restrict__ qkv) {
  int gid = blockIdx.x * 256 + threadIdx.x;  // BT * 2048 threads
  int c4 = (gid & 2047) * 4;
  int bt = gid >> 11;
  int b = bt >> 10, tt = bt & 1023;
  f32x4 wv[4];
#pragma unroll
  for (int j = 0; j < 4; ++j) wv[j] = *(const f32x4*)(conv_w + (c4 + j) * 4);
  float acc[4] = {0.f, 0.f, 0.f, 0.f};
#pragma unroll
  for (int i = 0; i < 4; ++i) {
    int ts = tt - 3 + i;
    if (ts >= 0) {
      u16x4 x = *(const u16x4*)(qkvb + (size_t)(b * 1024 + ts) * CONVC + c4);
#pragma unroll
      for (int j = 0; j < 4; ++j) acc[j] += bf2f(x[j]) * wv[j][i];
    }
  }
  u32x2 st;
  st[0] = pack2(siluf(acc[0]), siluf(acc[1]));
  st[1] = pack2(siluf(acc[2]), siluf(acc[3]));
  *(u32x2*)(qkv + (size_t)bt * CONVC + c4) = st;
}

// -------- l2 norm of q,k heads in place (bf16), q also * DK^-0.5 ------------
__global__ __launch_bounds__(256) void l2norm_kernel(u16* __restrict__ qkv) {
  int wid = blockIdx.x * 4 + (threadIdx.x >> 6);
  int l = threadIdx.x & 63;
  int tok = wid >> 5, slot = wid & 31;  // slot<16: q head, else k head
  u16* p = qkv + (size_t)tok * CONVC + slot * 128 + l * 2;
  float x0 = bf2f(p[0]), x1 = bf2f(p[1]);
  float ss = x0 * x0 + x1 * x1;
#pragma unroll
  for (int m = 1; m < 64; m <<= 1) ss += __shfl_xor(ss, m, 64);
  float sc = rsqrtf(ss + 1e-6f);
  if (slot < 16) sc *= 0.08838834764831845f;  // DK^-0.5
  *(u32*)p = pack2(x0 * sc, x1 * sc);
}

// -------- bd[(b*32+h)][t][2] = {sigmoid(bb), exp(-exp(A_log)*softplus)} -----
__global__ __launch_bounds__(256) void betadecay_kernel(
    const float* __restrict__ ba, const float* __restrict__ A_log,
    const float* __restrict__ dt_bias, float* __restrict__ bd) {
  int idx = blockIdx.x * 256 + threadIdx.x;  // BT*HV
  int h = idx & 31;
  int tok = idx >> 5;
  int b = tok >> 10, tt = tok & 1023;
  float bb = ba[(size_t)tok * 64 + h];
  float aa = ba[(size_t)tok * 64 + 32 + h];
  float bet = 1.f / (1.f + expf(-bb));
  float x = aa + dt_bias[h];
  float sp = (x > 20.f) ? x : log1pf(expf(x));
  float dec = expf(-expf(A_log[h]) * sp);
  size_t o = (((size_t)(b * 32 + h)) * 1024 + tt) * 2;
  bd[o] = bet;
  bd[o + 1] = dec;
}

// -------- gated delta rule scan (bf16 q/k/v, f32 state) ---------------------
// grid (8 vc, 64 bh), block 256 = 4 waves. Wave: 4 v-cols x 16-lane k-split,
// s[8]/lane. beta/decay staged in LDS (keeps SMEM out of the loop; all loop
// lgkm ops are in-order DS). 4-deep register prefetch ring for k/q/v.
__global__ __launch_bounds__(256) void scan_kernel(
    const u16* __restrict__ qkv, const float* __restrict__ bdg,
    u16* __restrict__ obf) {
  __shared__ __align__(16) float bd[2 * 1040];  // [t][2], padded for over-read
  int w = threadIdx.x >> 6, l = threadIdx.x & 63;
  int vc = blockIdx.x;
  int bh = blockIdx.y;
  int b = bh >> 5, h = bh & 31, hk = h >> 1;
  int col = vc * 16 + w * 4 + (l >> 4);
  int kg = l & 15;

  {  // stage this head's beta/decay: 2048 contiguous floats
    const float* src = bdg + (size_t)bh * 2048;
    f32x4 s0 = *(const f32x4*)(src + threadIdx.x * 8);
    f32x4 s1 = *(const f32x4*)(src + threadIdx.x * 8 + 4);
    *(f32x4*)(bd + threadIdx.x * 8) = s0;
    *(f32x4*)(bd + threadIdx.x * 8 + 4) = s1;
  }
  __syncthreads();

  const u16* qp = qkv + (size_t)b * 1024 * CONVC + hk * 128 + kg * 8;
  const u16* kp = qp + KEYDIM;
  const u16* vp = qkv + (size_t)b * 1024 * CONVC + 2 * KEYDIM + h * 128 + col;
  u16* op = obf + (size_t)b * 1024 * VALDIM + h * 128 + col;

  float s[8];
#pragma unroll
  for (int i = 0; i < 8; ++i) s[i] = 0.f;

  // 4-deep prefetch ring (over-reads past t=1023 land in adjacent ws buffers)
  bf16x8 kr[4], qr[4];
  float vr[4];
#pragma unroll
  for (int j = 0; j < 4; ++j) {
    kr[j] = *(const bf16x8*)(kp + (size_t)j * CONVC);
    qr[j] = *(const bf16x8*)(qp + (size_t)j * CONVC);
    vr[j] = bf2f(vp[(size_t)j * CONVC]);
  }
  qp += 4 * CONVC;
  kp += 4 * CONVC;
  vp += 4 * CONVC;

  f32x4 bdA = *(const f32x4*)(bd);
  f32x4 bdB = *(const f32x4*)(bd + 4);

  for (int t0 = 0; t0 < 1024; t0 += 4) {
    f32x4 cA = bdA, cB = bdB;
    bdA = *(const f32x4*)(bd + (t0 + 4) * 2);      // next group (pad-safe)
    bdB = *(const f32x4*)(bd + (t0 + 4) * 2 + 4);
#pragma unroll
    for (int j = 0; j < 4; ++j) {
      bf16x8 kc = kr[j], qc = qr[j];
      float vt = vr[j];
      float bet = (j == 0) ? cA[0] : (j == 1) ? cA[2] : (j == 2) ? cB[0] : cB[2];
      float dec = (j == 0) ? cA[1] : (j == 1) ? cA[3] : (j == 2) ? cB[1] : cB[3];
      // prefetch step t0+4+j
      kr[j] = *(const bf16x8*)(kp + (size_t)j * CONVC);
      qr[j] = *(const bf16x8*)(qp + (size_t)j * CONVC);
      vr[j] = bf2f(vp[(size_t)j * CONVC]);

      float kv[8], qv[8];
#pragma unroll
      for (int i = 0; i < 8; ++i) {
        kv[i] = bf2f((u16)kc[i]);
        qv[i] = bf2f((u16)qc[i]);
      }
#pragma unroll
      for (int i = 0; i < 8; ++i) s[i] *= dec;
      float d0 = fmaf(kv[1], s[1], kv[0] * s[0]);
      float d1 = fmaf(kv[3], s[3], kv[2] * s[2]);
      float d2 = fmaf(kv[5], s[5], kv[4] * s[4]);
      float d3 = fmaf(kv[7], s[7], kv[6] * s[6]);
      float dot = (d0 + d1) + (d2 + d3);
      dot += __shfl_xor(dot, 1, 64);
      dot += __shfl_xor(dot, 2, 64);
      dot += __shfl_xor(dot, 4, 64);
      dot += __shfl_xor(dot, 8, 64);
      float delta = (vt - dot) * bet;
#pragma unroll
      for (int i = 0; i < 8; ++i) s[i] = fmaf(kv[i], delta, s[i]);
      float e0 = fmaf(qv[1], s[1], qv[0] * s[0]);
      float e1 = fmaf(qv[3], s[3], qv[2] * s[2]);
      float e2 = fmaf(qv[5], s[5], qv[4] * s[4]);
      float e3 = fmaf(qv[7], s[7], qv[6] * s[6]);
      float dot2 = (e0 + e1) + (e2 + e3);
      dot2 += __shfl_xor(dot2, 1, 64);
      dot2 += __shfl_xor(dot2, 2, 64);
      dot2 += __shfl_xor(dot2, 4, 64);
      dot2 += __shfl_xor(dot2, 8, 64);
      if (kg == 0) *op = f2bf(dot2);
      op += VALDIM;
    }
    qp += 4 * CONVC;
    kp += 4 * CONVC;
    vp += 4 * CONVC;
  }
}

// -------- gate (silu(z)) + per-head RMSNorm, in-place over z ----------------
__global__ __launch_bounds__(256) void gatenorm_kernel(
    const u16* __restrict__ obf, u16* __restrict__ zb,
    const float* __restrict__ norm_w) {
  int wid = blockIdx.x * 4 + (threadIdx.x >> 6);
  int l = threadIdx.x & 63;
  int tok = wid >> 5, h = wid & 31;
  const u16* op = obf + (size_t)tok * VALDIM + h * 128 + l * 2;
  u16* zp = zb + (size_t)tok * VALDIM + h * 128 + l * 2;
  float o0 = bf2f(op[0]), o1 = bf2f(op[1]);
  float z0 = bf2f(zp[0]), z1 = bf2f(zp[1]);
  float g0 = o0 * siluf(z0);
  float g1 = o1 * siluf(z1);
  float ss = g0 * g0 + g1 * g1;
#pragma unroll
  for (int m = 1; m < 64; m <<= 1) ss += __shfl_xor(ss, m, 64);
  float sc = rsqrtf(ss * (1.f / 128.f) + 1e-6f);
  int e = l * 2;
  *(u32*)zp = pack2(g0 * sc * norm_w[e], g1 * sc * norm_w[e + 1]);
}

// -------- m = silu(g) * u -> bf16 (in place over u) -------------------------
__global__ __launch_bounds__(256) void mact_kernel(const u16* __restrict__ g,
                                                   u16* __restrict__ u) {
  size_t i = ((size_t)blockIdx.x * 256 + threadIdx.x) * 8;
  bf16x8 gv = *(const bf16x8*)(g + i);
  bf16x8 uv = *(const bf16x8*)(u + i);
  u32x4 st;
#pragma unroll
  for (int j = 0; j < 4; ++j) {
    float a0 = siluf(bf2f((u16)gv[2 * j])) * bf2f((u16)uv[2 * j]);
    float a1 = siluf(bf2f((u16)gv[2 * j + 1])) * bf2f((u16)uv[2 * j + 1]);
    st[j] = pack2(a0, a1);
  }
  *(u32x4*)(u + i) = st;
}

// -------- diagnostic: encode ws_size into d_out[0] --------------------------
__global__ void diag_kernel(float* out, float val) { out[0] = val; }

extern "C" void kernel_launch(void* const* d_in, const int* in_sizes, int n_in,
                              void* d_out, int out_size, void* d_ws,
                              size_t ws_size, hipStream_t stream) {
  const float* hidden = (const float*)d_in[1];
  const float* residual = (const float*)d_in[2];
  const float* ln_in_w = (const float*)d_in[3];
  const float* ln_post_w = (const float*)d_in[4];
  const float* Wqkvz = (const float*)d_in[5];
  const float* Wba = (const float*)d_in[6];
  const float* conv_w = (const float*)d_in[7];
  const float* A_log = (const float*)d_in[8];
  const float* dt_bias = (const float*)d_in[9];
  const float* norm_w = (const float*)d_in[10];
  const float* Wout = (const float*)d_in[11];
  const float* Wgate = (const float*)d_in[12];
  const float* Wup = (const float*)d_in[13];
  const float* Wdown = (const float*)d_in[14];

  char* ws = (char*)d_ws;
  size_t off = 0;
  auto alloc = [&](size_t n) {
    char* p = ws + off;
    off = (off + n + 255) & ~(size_t)255;
    return p;
  };
  u16* wslot = (u16*)alloc((size_t)INTER * DMODEL * 2);       // 33.55 MB
  u16* hb = (u16*)alloc((size_t)BT * DMODEL * 2);             //  8.39 MB
  u16* qkvb = (u16*)alloc((size_t)BT * CONVC * 2);            // 33.55 MB
  u16* zb = (u16*)alloc((size_t)BT * VALDIM * 2);             // 16.78 MB
  u16* qkvc = (u16*)alloc((size_t)BT * CONVC * 2);            // 33.55 MB
  float* ba = (float*)alloc((size_t)BT * 64 * 4);             //  0.52 MB
  float* bdpack = (float*)alloc((size_t)64 * 1024 * 2 * 4);   //  0.52 MB
  u16* obf = (u16*)alloc((size_t)BT * VALDIM * 2);            // 16.78 MB
  if (off > ws_size) {                                        // ~143.7 MB total
    diag_kernel<<<1, 1, 0, stream>>>((float*)d_out, (float)(ws_size >> 20));
    return;
  }

  float* res1 = (float*)d_out;                        // part1 (dead before out)
  float* attn = (float*)d_out + (size_t)BT * DMODEL;  // part2
  float* res2 = attn;                                 // in-place
  u16* h2b = hb;                                      // hb dead after GEMM1/ba
  u16* gbuf = qkvc;                                   // qkvc dead after scan
  u16* ubuf = qkvb;                                   // qkvb dead after conv
  u16* mbuf = qkvb;                                   // in-place over u
  float* outp = (float*)d_out;                        // final (res1 dead)

  dim3 blk(256);

  // 1. res1 = hidden+residual; hb = rmsnorm(res1)
  resnorm_kernel<<<BT, blk, 0, stream>>>(hidden, residual, ln_in_w, res1, hb);

  // 2. qkv-slice GEMM: qkvb = hb @ Wqkvz[:, :8192]
  convert_transpose<<<dim3(CONVC / 32, DMODEL / 32), blk, 0, stream>>>(
      Wqkvz, QKVZ_N, wslot, DMODEL, CONVC);
  gemm_kernel<1><<<dim3(CONVC / 128, BT / 128), blk, 0, stream>>>(
      hb, wslot, qkvb, BT, CONVC, DMODEL);

  // 3. z-slice GEMM: zb = hb @ Wqkvz[:, 8192:]
  convert_transpose<<<dim3(VALDIM / 32, DMODEL / 32), blk, 0, stream>>>(
      Wqkvz + CONVC, QKVZ_N, wslot, DMODEL, VALDIM);
  gemm_kernel<1><<<dim3(VALDIM / 128, BT / 128), blk, 0, stream>>>(
      hb, wslot, zb, BT, VALDIM, DMODEL);

  // 4. ba = hb @ Wba
  ba_gemm_kernel<<<BT, blk, 0, stream>>>(hb, Wba, ba);

  // 5-7. conv+silu, l2norm(q,k), beta/decay (packed per-head layout)
  conv_silu_kernel<<<BT * 2048 / 256, blk, 0, stream>>>(qkvb, conv_w, qkvc);
  l2norm_kernel<<<BT * 32 / 4, blk, 0, stream>>>(qkvc);
  betadecay_kernel<<<BT * HV / 256, blk, 0, stream>>>(ba, A_log, dt_bias,
                                                      bdpack);

  // 8. gated delta rule scan
  scan_kernel<<<dim3(8, 64), blk, 0, stream>>>(qkvc, bdpack, obf);

  // 9. gate + per-head RMSNorm (in place over zb)
  gatenorm_kernel<<<BT * HV / 4, blk, 0, stream>>>(obf, zb, norm_w);

  // 10. attn = og @ Wout  (f32, into d_out part2)
  convert_transpose<<<dim3(DMODEL / 32, VALDIM / 32), blk, 0, stream>>>(
      Wout, DMODEL, wslot, VALDIM, DMODEL);
  gemm_kernel<0><<<dim3(DMODEL / 128, BT / 128), blk, 0, stream>>>(
      zb, wslot, attn, BT, DMODEL, VALDIM);

  // 11. res2 = attn + res1 (in place, part2); h2b = rmsnorm(res2)
  resnorm_kernel<<<BT, blk, 0, stream>>>(attn, res1, ln_post_w, res2, h2b);

  // 12-13. gate & up GEMMs (bf16 outs)
  convert_transpose<<<dim3(INTER / 32, DMODEL / 32), blk, 0, stream>>>(
      Wgate, INTER, wslot, DMODEL, INTER);
  gemm_kernel<1><<<dim3(INTER / 128, BT / 128), blk, 0, stream>>>(
      h2b, wslot, gbuf, BT, INTER, DMODEL);
  convert_transpose<<<dim3(INTER / 32, DMODEL / 32), blk, 0, stream>>>(
      Wup, INTER, wslot, DMODEL, INTER);
  gemm_kernel<1><<<dim3(INTER / 128, BT / 128), blk, 0, stream>>>(
      h2b, wslot, ubuf, BT, INTER, DMODEL);

  // 14. m = silu(g)*u (in place over u)
  mact_kernel<<<BT * INTER / 8 / 256, blk, 0, stream>>>(gbuf, ubuf);

  // 15. out = m @ Wdown (f32, d_out part1)
  convert_transpose<<<dim3(DMODEL / 32, INTER / 32), blk, 0, stream>>>(
      Wdown, DMODEL, wslot, INTER, DMODEL);
  gemm_kernel<0><<<dim3(DMODEL / 128, BT / 128), blk, 0, stream>>>(
      mbuf, wslot, outp, BT, DMODEL, INTER);
}

// Round 5
// 1237.295 us; speedup vs baseline: 1.3094x; 1.1027x over previous
//
#include <hip/hip_runtime.h>
#include <hip/hip_bf16.h>

typedef unsigned short u16;
typedef unsigned int u32;
typedef float f32x4 __attribute__((ext_vector_type(4)));
typedef short bf16x8 __attribute__((ext_vector_type(8)));
typedef unsigned short u16x4 __attribute__((ext_vector_type(4)));
typedef unsigned int u32x2 __attribute__((ext_vector_type(2)));
typedef unsigned int u32x4 __attribute__((ext_vector_type(4)));

#define BT 2048            // B*T
#define DMODEL 2048
#define HV 32
#define DK 128
#define KEYDIM 2048
#define VALDIM 4096
#define QKVZ_N 12288
#define CONVC 8192         // q,k,v channels
#define INTER 8192

__device__ __forceinline__ float bf2f(u16 v) {
  u32 u = ((u32)v) << 16;
  return __builtin_bit_cast(float, u);
}
__device__ __forceinline__ u16 f2bf(float f) {
  u32 u = __builtin_bit_cast(u32, f);
  u32 r = (u + 0x7fffu + ((u >> 16) & 1u)) >> 16;
  return (u16)r;
}
__device__ __forceinline__ u32 pack2(float a, float b) {
  return (u32)f2bf(a) | ((u32)f2bf(b) << 16);
}
__device__ __forceinline__ float siluf(float x) {
  return x / (1.f + expf(-x));
}

// 16-lane (DPP row) sum reduce: all 16 lanes end with the row sum.
// quad_perm xor1 (0xB1), quad_perm xor2 (0x4E), row_ror:4 (0x124), row_ror:8 (0x128)
__device__ __forceinline__ float row16_sum(float x) {
  int t;
  t = __builtin_amdgcn_update_dpp(0, __builtin_bit_cast(int, x), 0xB1, 0xf, 0xf, true);
  x += __builtin_bit_cast(float, t);
  t = __builtin_amdgcn_update_dpp(0, __builtin_bit_cast(int, x), 0x4E, 0xf, 0xf, true);
  x += __builtin_bit_cast(float, t);
  t = __builtin_amdgcn_update_dpp(0, __builtin_bit_cast(int, x), 0x124, 0xf, 0xf, true);
  x += __builtin_bit_cast(float, t);
  t = __builtin_amdgcn_update_dpp(0, __builtin_bit_cast(int, x), 0x128, 0xf, 0xf, true);
  x += __builtin_bit_cast(float, t);
  return x;
}

// -------- weight convert+transpose: W[K,N] f32 (row stride ldw) -> Wt[N,K] bf16
__global__ __launch_bounds__(256) void convert_transpose(
    const float* __restrict__ W, int ldw, u16* __restrict__ Wt, int K, int N) {
  __shared__ float tile[32][33];
  int n0 = blockIdx.x * 32, k0 = blockIdx.y * 32;
  int tx = threadIdx.x & 31, ty = threadIdx.x >> 5;  // ty 0..7
#pragma unroll
  for (int i = 0; i < 4; ++i) {
    int kk = ty + i * 8;
    tile[kk][tx] = W[(size_t)(k0 + kk) * ldw + n0 + tx];
  }
  __syncthreads();
#pragma unroll
  for (int i = 0; i < 4; ++i) {
    int nn = ty + i * 8;
    Wt[(size_t)(n0 + nn) * K + k0 + tx] = f2bf(tile[tx][nn]);
  }
}

// -------- fused residual add + gemma RMSNorm (a+b -> resout f32, norm -> bf16)
__global__ __launch_bounds__(256) void resnorm_kernel(
    const float* __restrict__ a, const float* __restrict__ b,
    const float* __restrict__ w, float* __restrict__ resout,
    u16* __restrict__ hb) {
  int tok = blockIdx.x, t = threadIdx.x;
  const float* ap = a + (size_t)tok * DMODEL + t * 8;
  const float* bp = b + (size_t)tok * DMODEL + t * 8;
  f32x4 x0 = *(const f32x4*)ap + *(const f32x4*)bp;
  f32x4 x1 = *(const f32x4*)(ap + 4) + *(const f32x4*)(bp + 4);
  *(f32x4*)(resout + (size_t)tok * DMODEL + t * 8) = x0;
  *(f32x4*)(resout + (size_t)tok * DMODEL + t * 8 + 4) = x1;
  float ss = 0.f;
#pragma unroll
  for (int j = 0; j < 4; ++j) ss += x0[j] * x0[j] + x1[j] * x1[j];
#pragma unroll
  for (int m = 1; m < 64; m <<= 1) ss += __shfl_xor(ss, m, 64);
  __shared__ float red[4];
  if ((t & 63) == 0) red[t >> 6] = ss;
  __syncthreads();
  ss = red[0] + red[1] + red[2] + red[3];
  float sc = rsqrtf(ss * (1.f / (float)DMODEL) + 1e-6f);
  const float* wp = w + t * 8;
  float y[8];
#pragma unroll
  for (int j = 0; j < 4; ++j) {
    y[j] = x0[j] * sc * (1.f + wp[j]);
    y[4 + j] = x1[j] * sc * (1.f + wp[4 + j]);
  }
  u32x4 st;
  st[0] = pack2(y[0], y[1]);
  st[1] = pack2(y[2], y[3]);
  st[2] = pack2(y[4], y[5]);
  st[3] = pack2(y[6], y[7]);
  *(u32x4*)(hb + (size_t)tok * DMODEL + t * 8) = st;
}

// -------- bf16 MFMA GEMM: C[M,N] = A[M,K]_bf16 * Bt[N,K]^T, OUT: 0=f32 1=bf16
__device__ __forceinline__ void async16(const void* g, void* l) {
  __builtin_amdgcn_global_load_lds(
      (const __attribute__((address_space(1))) u32*)g,
      (__attribute__((address_space(3))) u32*)l, 16, 0, 0);
}

template <int OUT>
__global__ __launch_bounds__(256) void gemm_kernel(
    const u16* __restrict__ A, const u16* __restrict__ Bt, void* __restrict__ Cv,
    int M, int N, int K) {
  __shared__ __align__(16) u16 Al[128 * 32];
  __shared__ __align__(16) u16 Bl[128 * 32];
  int tid = threadIdx.x;
  int w = tid >> 6, l = tid & 63;
  int wr = w >> 1, wc = w & 1;
  int m0 = blockIdx.y * 128, n0 = blockIdx.x * 128;
  int r15 = l & 15, kb = l >> 4;

  f32x4 acc[4][4] = {};

  for (int kt = 0; kt < K; kt += 32) {
#pragma unroll
    for (int c = 0; c < 2; ++c) {
      int gid = w * 128 + c * 64 + l;          // 16B granule id in tile
      int row = gid >> 2;
      int g = (gid & 3) ^ ((row >> 1) & 3);    // pre-swizzled source granule
      async16(A + (size_t)(m0 + row) * K + kt + g * 8, Al + gid * 8);
      async16(Bt + (size_t)(n0 + row) * K + kt + g * 8, Bl + gid * 8);
    }
    __syncthreads();
    bf16x8 aF[4], bF[4];
#pragma unroll
    for (int m = 0; m < 4; ++m) {
      int row = wr * 64 + m * 16 + r15;
      aF[m] = *(const bf16x8*)(Al + row * 32 + (kb ^ ((row >> 1) & 3)) * 8);
    }
#pragma unroll
    for (int n = 0; n < 4; ++n) {
      int row = wc * 64 + n * 16 + r15;
      bF[n] = *(const bf16x8*)(Bl + row * 32 + (kb ^ ((row >> 1) & 3)) * 8);
    }
#pragma unroll
    for (int m = 0; m < 4; ++m)
#pragma unroll
      for (int n = 0; n < 4; ++n)
        acc[m][n] = __builtin_amdgcn_mfma_f32_16x16x32_bf16(aF[m], bF[n],
                                                            acc[m][n], 0, 0, 0);
    __syncthreads();
  }

#pragma unroll
  for (int m = 0; m < 4; ++m)
#pragma unroll
    for (int n = 0; n < 4; ++n) {
      size_t base = (size_t)(m0 + wr * 64 + m * 16 + kb * 4) * N +
                    (n0 + wc * 64 + n * 16 + r15);
#pragma unroll
      for (int r = 0; r < 4; ++r) {
        if (OUT == 0)
          ((float*)Cv)[base + (size_t)r * N] = acc[m][n][r];
        else
          ((u16*)Cv)[base + (size_t)r * N] = f2bf(acc[m][n][r]);
      }
    }
}

// -------- ba = hb(bf16) @ Wba(f32 [2048,64]) --------------------------------
__global__ __launch_bounds__(256) void ba_gemm_kernel(
    const u16* __restrict__ hb, const float* __restrict__ Wba,
    float* __restrict__ ba) {
  int m = blockIdx.x;
  int t = threadIdx.x;
  int n = t & 63, kq = t >> 6;
  const u16* a = hb + (size_t)m * DMODEL + kq * 512;
  const float* wp = Wba + (size_t)kq * 512 * 64 + n;
  float sum = 0.f;
  for (int i = 0; i < 512; ++i)
    sum += bf2f(a[i]) * wp[(size_t)i * 64];
  __shared__ float red[256];
  red[t] = sum;
  __syncthreads();
  if (t < 64)
    ba[(size_t)m * 64 + t] = red[t] + red[t + 64] + red[t + 128] + red[t + 192];
}

// -------- causal depthwise conv (K=4) + SiLU, bf16 in/out -------------------
__global__ __launch_bounds__(256) void conv_silu_kernel(
    const u16* __restrict__ qkvb, const float* __restrict__ conv_w,
    u16* __restrict__ qkv) {
  int gid = blockIdx.x * 256 + threadIdx.x;  // BT * 2048 threads
  int c4 = (gid & 2047) * 4;
  int bt = gid >> 11;
  int b = bt >> 10, tt = bt & 1023;
  f32x4 wv[4];
#pragma unroll
  for (int j = 0; j < 4; ++j) wv[j] = *(const f32x4*)(conv_w + (c4 + j) * 4);
  float acc[4] = {0.f, 0.f, 0.f, 0.f};
#pragma unroll
  for (int i = 0; i < 4; ++i) {
    int ts = tt - 3 + i;
    if (ts >= 0) {
      u16x4 x = *(const u16x4*)(qkvb + (size_t)(b * 1024 + ts) * CONVC + c4);
#pragma unroll
      for (int j = 0; j < 4; ++j) acc[j] += bf2f(x[j]) * wv[j][i];
    }
  }
  u32x2 st;
  st[0] = pack2(siluf(acc[0]), siluf(acc[1]));
  st[1] = pack2(siluf(acc[2]), siluf(acc[3]));
  *(u32x2*)(qkv + (size_t)bt * CONVC + c4) = st;
}

// -------- l2 norm of q,k heads in place (bf16), q also * DK^-0.5 ------------
__global__ __launch_bounds__(256) void l2norm_kernel(u16* __restrict__ qkv) {
  int wid = blockIdx.x * 4 + (threadIdx.x >> 6);
  int l = threadIdx.x & 63;
  int tok = wid >> 5, slot = wid & 31;  // slot<16: q head, else k head
  u16* p = qkv + (size_t)tok * CONVC + slot * 128 + l * 2;
  float x0 = bf2f(p[0]), x1 = bf2f(p[1]);
  float ss = x0 * x0 + x1 * x1;
#pragma unroll
  for (int m = 1; m < 64; m <<= 1) ss += __shfl_xor(ss, m, 64);
  float sc = rsqrtf(ss + 1e-6f);
  if (slot < 16) sc *= 0.08838834764831845f;  // DK^-0.5
  *(u32*)p = pack2(x0 * sc, x1 * sc);
}

// -------- bd[(b*32+h)][t][2] = {sigmoid(bb), exp(-exp(A_log)*softplus)} -----
__global__ __launch_bounds__(256) void betadecay_kernel(
    const float* __restrict__ ba, const float* __restrict__ A_log,
    const float* __restrict__ dt_bias, float* __restrict__ bd) {
  int idx = blockIdx.x * 256 + threadIdx.x;  // BT*HV
  int h = idx & 31;
  int tok = idx >> 5;
  int b = tok >> 10, tt = tok & 1023;
  float bb = ba[(size_t)tok * 64 + h];
  float aa = ba[(size_t)tok * 64 + 32 + h];
  float bet = 1.f / (1.f + expf(-bb));
  float x = aa + dt_bias[h];
  float sp = (x > 20.f) ? x : log1pf(expf(x));
  float dec = expf(-expf(A_log[h]) * sp);
  size_t o = (((size_t)(b * 32 + h)) * 1024 + tt) * 2;
  bd[o] = bet;
  bd[o + 1] = dec;
}

// -------- gated delta rule scan (bf16 q/k/v, f32 state) ---------------------
// grid (8 vc, 64 bh), block 256 = 4 waves. Wave: 4 v-cols x 16-lane k-split,
// s[8]/lane. beta/decay staged in LDS; 4-deep register prefetch ring for
// k/q/v; 16-lane reductions via DPP (VALU) instead of ds_swizzle shuffles.
__global__ __launch_bounds__(256) void scan_kernel(
    const u16* __restrict__ qkv, const float* __restrict__ bdg,
    u16* __restrict__ obf) {
  __shared__ __align__(16) float bd[2 * 1040];  // [t][2], padded for over-read
  int w = threadIdx.x >> 6, l = threadIdx.x & 63;
  int vc = blockIdx.x;
  int bh = blockIdx.y;
  int b = bh >> 5, h = bh & 31, hk = h >> 1;
  int col = vc * 16 + w * 4 + (l >> 4);
  int kg = l & 15;

  {  // stage this head's beta/decay: 2048 contiguous floats
    const float* src = bdg + (size_t)bh * 2048;
    f32x4 s0 = *(const f32x4*)(src + threadIdx.x * 8);
    f32x4 s1 = *(const f32x4*)(src + threadIdx.x * 8 + 4);
    *(f32x4*)(bd + threadIdx.x * 8) = s0;
    *(f32x4*)(bd + threadIdx.x * 8 + 4) = s1;
  }
  __syncthreads();

  const u16* qp = qkv + (size_t)b * 1024 * CONVC + hk * 128 + kg * 8;
  const u16* kp = qp + KEYDIM;
  const u16* vp = qkv + (size_t)b * 1024 * CONVC + 2 * KEYDIM + h * 128 + col;
  u16* op = obf + (size_t)b * 1024 * VALDIM + h * 128 + col;

  float s[8];
#pragma unroll
  for (int i = 0; i < 8; ++i) s[i] = 0.f;

  // 4-deep prefetch ring (over-reads past t=1023 land in adjacent ws buffers)
  bf16x8 kr[4], qr[4];
  float vr[4];
#pragma unroll
  for (int j = 0; j < 4; ++j) {
    kr[j] = *(const bf16x8*)(kp + (size_t)j * CONVC);
    qr[j] = *(const bf16x8*)(qp + (size_t)j * CONVC);
    vr[j] = bf2f(vp[(size_t)j * CONVC]);
  }
  qp += 4 * CONVC;
  kp += 4 * CONVC;
  vp += 4 * CONVC;

  f32x4 bdA = *(const f32x4*)(bd);
  f32x4 bdB = *(const f32x4*)(bd + 4);

  for (int t0 = 0; t0 < 1024; t0 += 4) {
    f32x4 cA = bdA, cB = bdB;
    bdA = *(const f32x4*)(bd + (t0 + 4) * 2);      // next group (pad-safe)
    bdB = *(const f32x4*)(bd + (t0 + 4) * 2 + 4);
#pragma unroll
    for (int j = 0; j < 4; ++j) {
      bf16x8 kc = kr[j], qc = qr[j];
      float vt = vr[j];
      float bet = (j == 0) ? cA[0] : (j == 1) ? cA[2] : (j == 2) ? cB[0] : cB[2];
      float dec = (j == 0) ? cA[1] : (j == 1) ? cA[3] : (j == 2) ? cB[1] : cB[3];
      // prefetch step t0+4+j
      kr[j] = *(const bf16x8*)(kp + (size_t)j * CONVC);
      qr[j] = *(const bf16x8*)(qp + (size_t)j * CONVC);
      vr[j] = bf2f(vp[(size_t)j * CONVC]);

      float kv[8], qv[8];
#pragma unroll
      for (int i = 0; i < 8; ++i) {
        kv[i] = bf2f((u16)kc[i]);
        qv[i] = bf2f((u16)qc[i]);
      }
#pragma unroll
      for (int i = 0; i < 8; ++i) s[i] *= dec;
      float d0 = fmaf(kv[1], s[1], kv[0] * s[0]);
      float d1 = fmaf(kv[3], s[3], kv[2] * s[2]);
      float d2 = fmaf(kv[5], s[5], kv[4] * s[4]);
      float d3 = fmaf(kv[7], s[7], kv[6] * s[6]);
      float dot = row16_sum((d0 + d1) + (d2 + d3));
      float delta = (vt - dot) * bet;
#pragma unroll
      for (int i = 0; i < 8; ++i) s[i] = fmaf(kv[i], delta, s[i]);
      float e0 = fmaf(qv[1], s[1], qv[0] * s[0]);
      float e1 = fmaf(qv[3], s[3], qv[2] * s[2]);
      float e2 = fmaf(qv[5], s[5], qv[4] * s[4]);
      float e3 = fmaf(qv[7], s[7], qv[6] * s[6]);
      float dot2 = row16_sum((e0 + e1) + (e2 + e3));
      if (kg == 0) *op = f2bf(dot2);
      op += VALDIM;
    }
    qp += 4 * CONVC;
    kp += 4 * CONVC;
    vp += 4 * CONVC;
  }
}

// -------- gate (silu(z)) + per-head RMSNorm, in-place over z ----------------
__global__ __launch_bounds__(256) void gatenorm_kernel(
    const u16* __restrict__ obf, u16* __restrict__ zb,
    const float* __restrict__ norm_w) {
  int wid = blockIdx.x * 4 + (threadIdx.x >> 6);
  int l = threadIdx.x & 63;
  int tok = wid >> 5, h = wid & 31;
  const u16* op = obf + (size_t)tok * VALDIM + h * 128 + l * 2;
  u16* zp = zb + (size_t)tok * VALDIM + h * 128 + l * 2;
  float o0 = bf2f(op[0]), o1 = bf2f(op[1]);
  float z0 = bf2f(zp[0]), z1 = bf2f(zp[1]);
  float g0 = o0 * siluf(z0);
  float g1 = o1 * siluf(z1);
  float ss = g0 * g0 + g1 * g1;
#pragma unroll
  for (int m = 1; m < 64; m <<= 1) ss += __shfl_xor(ss, m, 64);
  float sc = rsqrtf(ss * (1.f / 128.f) + 1e-6f);
  int e = l * 2;
  *(u32*)zp = pack2(g0 * sc * norm_w[e], g1 * sc * norm_w[e + 1]);
}

// -------- m = silu(g) * u -> bf16 (in place over u) -------------------------
__global__ __launch_bounds__(256) void mact_kernel(const u16* __restrict__ g,
                                                   u16* __restrict__ u) {
  size_t i = ((size_t)blockIdx.x * 256 + threadIdx.x) * 8;
  bf16x8 gv = *(const bf16x8*)(g + i);
  bf16x8 uv = *(const bf16x8*)(u + i);
  u32x4 st;
#pragma unroll
  for (int j = 0; j < 4; ++j) {
    float a0 = siluf(bf2f((u16)gv[2 * j])) * bf2f((u16)uv[2 * j]);
    float a1 = siluf(bf2f((u16)gv[2 * j + 1])) * bf2f((u16)uv[2 * j + 1]);
    st[j] = pack2(a0, a1);
  }
  *(u32x4*)(u + i) = st;
}

// -------- diagnostic: encode ws_size into d_out[0] --------------------------
__global__ void diag_kernel(float* out, float val) { out[0] = val; }

extern "C" void kernel_launch(void* const* d_in, const int* in_sizes, int n_in,
                              void* d_out, int out_size, void* d_ws,
                              size_t ws_size, hipStream_t stream) {
  const float* hidden = (const float*)d_in[1];
  const float* residual = (const float*)d_in[2];
  const float* ln_in_w = (const float*)d_in[3];
  const float* ln_post_w = (const float*)d_in[4];
  const float* Wqkvz = (const float*)d_in[5];
  const float* Wba = (const float*)d_in[6];
  const float* conv_w = (const float*)d_in[7];
  const float* A_log = (const float*)d_in[8];
  const float* dt_bias = (const float*)d_in[9];
  const float* norm_w = (const float*)d_in[10];
  const float* Wout = (const float*)d_in[11];
  const float* Wgate = (const float*)d_in[12];
  const float* Wup = (const float*)d_in[13];
  const float* Wdown = (const float*)d_in[14];

  char* ws = (char*)d_ws;
  size_t off = 0;
  auto alloc = [&](size_t n) {
    char* p = ws + off;
    off = (off + n + 255) & ~(size_t)255;
    return p;
  };
  u16* wslot = (u16*)alloc((size_t)INTER * DMODEL * 2);       // 33.55 MB
  u16* hb = (u16*)alloc((size_t)BT * DMODEL * 2);             //  8.39 MB
  u16* qkvb = (u16*)alloc((size_t)BT * CONVC * 2);            // 33.55 MB
  u16* zb = (u16*)alloc((size_t)BT * VALDIM * 2);             // 16.78 MB
  u16* qkvc = (u16*)alloc((size_t)BT * CONVC * 2);            // 33.55 MB
  float* ba = (float*)alloc((size_t)BT * 64 * 4);             //  0.52 MB
  float* bdpack = (float*)alloc((size_t)64 * 1024 * 2 * 4);   //  0.52 MB
  u16* obf = (u16*)alloc((size_t)BT * VALDIM * 2);            // 16.78 MB
  if (off > ws_size) {                                        // ~143.7 MB total
    diag_kernel<<<1, 1, 0, stream>>>((float*)d_out, (float)(ws_size >> 20));
    return;
  }

  float* res1 = (float*)d_out;                        // part1 (dead before out)
  float* attn = (float*)d_out + (size_t)BT * DMODEL;  // part2
  float* res2 = attn;                                 // in-place
  u16* h2b = hb;                                      // hb dead after GEMM1/ba
  u16* gbuf = qkvc;                                   // qkvc dead after scan
  u16* ubuf = qkvb;                                   // qkvb dead after conv
  u16* mbuf = qkvb;                                   // in-place over u
  float* outp = (float*)d_out;                        // final (res1 dead)

  dim3 blk(256);

  // 1. res1 = hidden+residual; hb = rmsnorm(res1)
  resnorm_kernel<<<BT, blk, 0, stream>>>(hidden, residual, ln_in_w, res1, hb);

  // 2. qkv-slice GEMM: qkvb = hb @ Wqkvz[:, :8192]
  convert_transpose<<<dim3(CONVC / 32, DMODEL / 32), blk, 0, stream>>>(
      Wqkvz, QKVZ_N, wslot, DMODEL, CONVC);
  gemm_kernel<1><<<dim3(CONVC / 128, BT / 128), blk, 0, stream>>>(
      hb, wslot, qkvb, BT, CONVC, DMODEL);

  // 3. z-slice GEMM: zb = hb @ Wqkvz[:, 8192:]
  convert_transpose<<<dim3(VALDIM / 32, DMODEL / 32), blk, 0, stream>>>(
      Wqkvz + CONVC, QKVZ_N, wslot, DMODEL, VALDIM);
  gemm_kernel<1><<<dim3(VALDIM / 128, BT / 128), blk, 0, stream>>>(
      hb, wslot, zb, BT, VALDIM, DMODEL);

  // 4. ba = hb @ Wba
  ba_gemm_kernel<<<BT, blk, 0, stream>>>(hb, Wba, ba);

  // 5-7. conv+silu, l2norm(q,k), beta/decay (packed per-head layout)
  conv_silu_kernel<<<BT * 2048 / 256, blk, 0, stream>>>(qkvb, conv_w, qkvc);
  l2norm_kernel<<<BT * 32 / 4, blk, 0, stream>>>(qkvc);
  betadecay_kernel<<<BT * HV / 256, blk, 0, stream>>>(ba, A_log, dt_bias,
                                                      bdpack);

  // 8. gated delta rule scan
  scan_kernel<<<dim3(8, 64), blk, 0, stream>>>(qkvc, bdpack, obf);

  // 9. gate + per-head RMSNorm (in place over zb)
  gatenorm_kernel<<<BT * HV / 4, blk, 0, stream>>>(obf, zb, norm_w);

  // 10. attn = og @ Wout  (f32, into d_out part2)
  convert_transpose<<<dim3(DMODEL / 32, VALDIM / 32), blk, 0, stream>>>(
      Wout, DMODEL, wslot, VALDIM, DMODEL);
  gemm_kernel<0><<<dim3(DMODEL / 128, BT / 128), blk, 0, stream>>>(
      zb, wslot, attn, BT, DMODEL, VALDIM);

  // 11. res2 = attn + res1 (in place, part2); h2b = rmsnorm(res2)
  resnorm_kernel<<<BT, blk, 0, stream>>>(attn, res1, ln_post_w, res2, h2b);

  // 12-13. gate & up GEMMs (bf16 outs)
  convert_transpose<<<dim3(INTER / 32, DMODEL / 32), blk, 0, stream>>>(
      Wgate, INTER, wslot, DMODEL, INTER);
  gemm_kernel<1><<<dim3(INTER / 128, BT / 128), blk, 0, stream>>>(
      h2b, wslot, gbuf, BT, INTER, DMODEL);
  convert_transpose<<<dim3(INTER / 32, DMODEL / 32), blk, 0, stream>>>(
      Wup, INTER, wslot, DMODEL, INTER);
  gemm_kernel<1><<<dim3(INTER / 128, BT / 128), blk, 0, stream>>>(
      h2b, wslot, ubuf, BT, INTER, DMODEL);

  // 14. m = silu(g)*u (in place over u)
  mact_kernel<<<BT * INTER / 8 / 256, blk, 0, stream>>>(gbuf, ubuf);

  // 15. out = m @ Wdown (f32, d_out part1)
  convert_transpose<<<dim3(DMODEL / 32, INTER / 32), blk, 0, stream>>>(
      Wdown, DMODEL, wslot, INTER, DMODEL);
  gemm_kernel<0><<<dim3(DMODEL / 128, BT / 128), blk, 0, stream>>>(
      mbuf, wslot, outp, BT, DMODEL, INTER);
}

// Round 6
// 1035.748 us; speedup vs baseline: 1.5642x; 1.1946x over previous
//
#include <hip/hip_runtime.h>
#include <hip/hip_bf16.h>

typedef unsigned short u16;
typedef unsigned int u32;
typedef float f32x4 __attribute__((ext_vector_type(4)));
typedef short bf16x8 __attribute__((ext_vector_type(8)));
typedef unsigned short u16x4 __attribute__((ext_vector_type(4)));
typedef unsigned int u32x2 __attribute__((ext_vector_type(2)));
typedef unsigned int u32x4 __attribute__((ext_vector_type(4)));

#define BT 2048            // B*T
#define DMODEL 2048
#define HV 32
#define DK 128
#define KEYDIM 2048
#define VALDIM 4096
#define QKVZ_N 12288
#define CONVC 8192         // q,k,v channels
#define INTER 8192

__device__ __forceinline__ float bf2f(u16 v) {
  u32 u = ((u32)v) << 16;
  return __builtin_bit_cast(float, u);
}
__device__ __forceinline__ u16 f2bf(float f) {
  u32 u = __builtin_bit_cast(u32, f);
  u32 r = (u + 0x7fffu + ((u >> 16) & 1u)) >> 16;
  return (u16)r;
}
__device__ __forceinline__ u32 pack2(float a, float b) {
  return (u32)f2bf(a) | ((u32)f2bf(b) << 16);
}
__device__ __forceinline__ float siluf(float x) {
  return x / (1.f + expf(-x));
}

// -------- weight convert+transpose: W[K,N] f32 (row stride ldw) -> Wt[N,K] bf16
__global__ __launch_bounds__(256) void convert_transpose(
    const float* __restrict__ W, int ldw, u16* __restrict__ Wt, int K, int N) {
  __shared__ float tile[32][33];
  int n0 = blockIdx.x * 32, k0 = blockIdx.y * 32;
  int tx = threadIdx.x & 31, ty = threadIdx.x >> 5;  // ty 0..7
#pragma unroll
  for (int i = 0; i < 4; ++i) {
    int kk = ty + i * 8;
    tile[kk][tx] = W[(size_t)(k0 + kk) * ldw + n0 + tx];
  }
  __syncthreads();
#pragma unroll
  for (int i = 0; i < 4; ++i) {
    int nn = ty + i * 8;
    Wt[(size_t)(n0 + nn) * K + k0 + tx] = f2bf(tile[tx][nn]);
  }
}

// -------- fused residual add + gemma RMSNorm (a+b -> resout f32, norm -> bf16)
__global__ __launch_bounds__(256) void resnorm_kernel(
    const float* __restrict__ a, const float* __restrict__ b,
    const float* __restrict__ w, float* __restrict__ resout,
    u16* __restrict__ hb) {
  int tok = blockIdx.x, t = threadIdx.x;
  const float* ap = a + (size_t)tok * DMODEL + t * 8;
  const float* bp = b + (size_t)tok * DMODEL + t * 8;
  f32x4 x0 = *(const f32x4*)ap + *(const f32x4*)bp;
  f32x4 x1 = *(const f32x4*)(ap + 4) + *(const f32x4*)(bp + 4);
  *(f32x4*)(resout + (size_t)tok * DMODEL + t * 8) = x0;
  *(f32x4*)(resout + (size_t)tok * DMODEL + t * 8 + 4) = x1;
  float ss = 0.f;
#pragma unroll
  for (int j = 0; j < 4; ++j) ss += x0[j] * x0[j] + x1[j] * x1[j];
#pragma unroll
  for (int m = 1; m < 64; m <<= 1) ss += __shfl_xor(ss, m, 64);
  __shared__ float red[4];
  if ((t & 63) == 0) red[t >> 6] = ss;
  __syncthreads();
  ss = red[0] + red[1] + red[2] + red[3];
  float sc = rsqrtf(ss * (1.f / (float)DMODEL) + 1e-6f);
  const float* wp = w + t * 8;
  float y[8];
#pragma unroll
  for (int j = 0; j < 4; ++j) {
    y[j] = x0[j] * sc * (1.f + wp[j]);
    y[4 + j] = x1[j] * sc * (1.f + wp[4 + j]);
  }
  u32x4 st;
  st[0] = pack2(y[0], y[1]);
  st[1] = pack2(y[2], y[3]);
  st[2] = pack2(y[4], y[5]);
  st[3] = pack2(y[6], y[7]);
  *(u32x4*)(hb + (size_t)tok * DMODEL + t * 8) = st;
}

// -------- bf16 MFMA GEMM: C[M,N] = A[M,K]_bf16 * Bt[N,K]^T, OUT: 0=f32 1=bf16
__device__ __forceinline__ void async16(const void* g, void* l) {
  __builtin_amdgcn_global_load_lds(
      (const __attribute__((address_space(1))) u32*)g,
      (__attribute__((address_space(3))) u32*)l, 16, 0, 0);
}

template <int OUT>
__global__ __launch_bounds__(256) void gemm_kernel(
    const u16* __restrict__ A, const u16* __restrict__ Bt, void* __restrict__ Cv,
    int M, int N, int K) {
  __shared__ __align__(16) u16 Al[128 * 32];
  __shared__ __align__(16) u16 Bl[128 * 32];
  int tid = threadIdx.x;
  int w = tid >> 6, l = tid & 63;
  int wr = w >> 1, wc = w & 1;
  int m0 = blockIdx.y * 128, n0 = blockIdx.x * 128;
  int r15 = l & 15, kb = l >> 4;

  f32x4 acc[4][4] = {};

  for (int kt = 0; kt < K; kt += 32) {
#pragma unroll
    for (int c = 0; c < 2; ++c) {
      int gid = w * 128 + c * 64 + l;          // 16B granule id in tile
      int row = gid >> 2;
      int g = (gid & 3) ^ ((row >> 1) & 3);    // pre-swizzled source granule
      async16(A + (size_t)(m0 + row) * K + kt + g * 8, Al + gid * 8);
      async16(Bt + (size_t)(n0 + row) * K + kt + g * 8, Bl + gid * 8);
    }
    __syncthreads();
    bf16x8 aF[4], bF[4];
#pragma unroll
    for (int m = 0; m < 4; ++m) {
      int row = wr * 64 + m * 16 + r15;
      aF[m] = *(const bf16x8*)(Al + row * 32 + (kb ^ ((row >> 1) & 3)) * 8);
    }
#pragma unroll
    for (int n = 0; n < 4; ++n) {
      int row = wc * 64 + n * 16 + r15;
      bF[n] = *(const bf16x8*)(Bl + row * 32 + (kb ^ ((row >> 1) & 3)) * 8);
    }
#pragma unroll
    for (int m = 0; m < 4; ++m)
#pragma unroll
      for (int n = 0; n < 4; ++n)
        acc[m][n] = __builtin_amdgcn_mfma_f32_16x16x32_bf16(aF[m], bF[n],
                                                            acc[m][n], 0, 0, 0);
    __syncthreads();
  }

#pragma unroll
  for (int m = 0; m < 4; ++m)
#pragma unroll
    for (int n = 0; n < 4; ++n) {
      size_t base = (size_t)(m0 + wr * 64 + m * 16 + kb * 4) * N +
                    (n0 + wc * 64 + n * 16 + r15);
#pragma unroll
      for (int r = 0; r < 4; ++r) {
        if (OUT == 0)
          ((float*)Cv)[base + (size_t)r * N] = acc[m][n][r];
        else
          ((u16*)Cv)[base + (size_t)r * N] = f2bf(acc[m][n][r]);
      }
    }
}

// -------- ba = hb(bf16) @ Wba(f32 [2048,64]) --------------------------------
__global__ __launch_bounds__(256) void ba_gemm_kernel(
    const u16* __restrict__ hb, const float* __restrict__ Wba,
    float* __restrict__ ba) {
  int m = blockIdx.x;
  int t = threadIdx.x;
  int n = t & 63, kq = t >> 6;
  const u16* a = hb + (size_t)m * DMODEL + kq * 512;
  const float* wp = Wba + (size_t)kq * 512 * 64 + n;
  float sum = 0.f;
  for (int i = 0; i < 512; ++i)
    sum += bf2f(a[i]) * wp[(size_t)i * 64];
  __shared__ float red[256];
  red[t] = sum;
  __syncthreads();
  if (t < 64)
    ba[(size_t)m * 64 + t] = red[t] + red[t + 64] + red[t + 128] + red[t + 192];
}

// -------- causal depthwise conv (K=4) + SiLU, bf16 in/out -------------------
__global__ __launch_bounds__(256) void conv_silu_kernel(
    const u16* __restrict__ qkvb, const float* __restrict__ conv_w,
    u16* __restrict__ qkv) {
  int gid = blockIdx.x * 256 + threadIdx.x;  // BT * 2048 threads
  int c4 = (gid & 2047) * 4;
  int bt = gid >> 11;
  int b = bt >> 10, tt = bt & 1023;
  f32x4 wv[4];
#pragma unroll
  for (int j = 0; j < 4; ++j) wv[j] = *(const f32x4*)(conv_w + (c4 + j) * 4);
  float acc[4] = {0.f, 0.f, 0.f, 0.f};
#pragma unroll
  for (int i = 0; i < 4; ++i) {
    int ts = tt - 3 + i;
    if (ts >= 0) {
      u16x4 x = *(const u16x4*)(qkvb + (size_t)(b * 1024 + ts) * CONVC + c4);
#pragma unroll
      for (int j = 0; j < 4; ++j) acc[j] += bf2f(x[j]) * wv[j][i];
    }
  }
  u32x2 st;
  st[0] = pack2(siluf(acc[0]), siluf(acc[1]));
  st[1] = pack2(siluf(acc[2]), siluf(acc[3]));
  *(u32x2*)(qkv + (size_t)bt * CONVC + c4) = st;
}

// -------- l2 norm of q,k heads in place (bf16), q also * DK^-0.5 ------------
__global__ __launch_bounds__(256) void l2norm_kernel(u16* __restrict__ qkv) {
  int wid = blockIdx.x * 4 + (threadIdx.x >> 6);
  int l = threadIdx.x & 63;
  int tok = wid >> 5, slot = wid & 31;  // slot<16: q head, else k head
  u16* p = qkv + (size_t)tok * CONVC + slot * 128 + l * 2;
  float x0 = bf2f(p[0]), x1 = bf2f(p[1]);
  float ss = x0 * x0 + x1 * x1;
#pragma unroll
  for (int m = 1; m < 64; m <<= 1) ss += __shfl_xor(ss, m, 64);
  float sc = rsqrtf(ss + 1e-6f);
  if (slot < 16) sc *= 0.08838834764831845f;  // DK^-0.5
  *(u32*)p = pack2(x0 * sc, x1 * sc);
}

// -------- bd[(b*32+h)][t][2] = {sigmoid(bb), exp(-exp(A_log)*softplus)} -----
__global__ __launch_bounds__(256) void betadecay_kernel(
    const float* __restrict__ ba, const float* __restrict__ A_log,
    const float* __restrict__ dt_bias, float* __restrict__ bd) {
  int idx = blockIdx.x * 256 + threadIdx.x;  // BT*HV
  int h = idx & 31;
  int tok = idx >> 5;
  int b = tok >> 10, tt = tok & 1023;
  float bb = ba[(size_t)tok * 64 + h];
  float aa = ba[(size_t)tok * 64 + 32 + h];
  float bet = 1.f / (1.f + expf(-bb));
  float x = aa + dt_bias[h];
  float sp = (x > 20.f) ? x : log1pf(expf(x));
  float dec = expf(-expf(A_log[h]) * sp);
  size_t o = (((size_t)(b * 32 + h)) * 1024 + tt) * 2;
  bd[o] = bet;
  bd[o + 1] = dec;
}

// ======================= chunked delta-rule scan ============================
// Chunk length 64. Within chunk (local t, chunk-start state S0):
//   b_t = sum_{m<=t} ln(gamma_m);  B_t = exp(b_t)
//   A_tj = beta_t exp(b_t-b_j) (k_t.k_j)   (j<t)
//   (I+A) delta = rhs,  rhs_t = beta_t (v_t - B_t (k_t^T S0))
//   o_t = B_t (q_t^T S0) + sum_{j<=t} exp(b_t-b_j)(q_t.k_j) delta_j
//   S_next = B_63 S0 + sum_j exp(b_63-b_j) k_j delta_j^T
// prep_kernel (parallel over all 16x64 chunk-heads): T=(I+A)^-1 bf16,
// P (masked scaled QK^T) bf16, KtT (scaled K, transposed) bf16, B vec f32.
// chunk_scan_kernel (grid 4 dv-slices x 64 bh): sequential over 16 chunks,
// 5 small MFMA products per chunk; state f32 in accumulators + bf16 LDS copy.

__global__ __launch_bounds__(256) void prep_kernel(
    const u16* __restrict__ qkvc, const float* __restrict__ bdpack,
    u16* __restrict__ Tg, u16* __restrict__ Pg, u16* __restrict__ KtTg,
    float* __restrict__ Bvec) {
  __shared__ __align__(16) u16 Kl[64 * 128];
  __shared__ __align__(16) u16 Ql[64 * 128];
  __shared__ __align__(16) float Af[64 * 64];
  __shared__ __align__(16) float Tf[64 * 64];
  __shared__ float lgl[64], bl[64], betal[64];
  int tid = threadIdx.x;
  int w = tid >> 6, l = tid & 63;
  int r15 = l & 15, kb = l >> 4;
  int c = blockIdx.x, bh = blockIdx.y;
  int b = bh >> 5, h = bh & 31, hk = h >> 1;
  size_t tok0 = (size_t)b * 1024 + c * 64;
  int ch = bh * 16 + c;  // chunk-head index

  // stage K, Q tiles [64][128] bf16
#pragma unroll
  for (int rep = 0; rep < 4; ++rep) {
    int gid = w * 256 + rep * 64 + l;
    int row = gid >> 4, seg = gid & 15;
    const u16* srcq = qkvc + (tok0 + row) * CONVC + hk * 128 + seg * 8;
    async16(srcq, Ql + gid * 8);
    async16(srcq + KEYDIM, Kl + gid * 8);
  }
  if (tid < 64) {
    size_t o = ((size_t)bh * 1024 + c * 64 + tid) * 2;
    betal[tid] = bdpack[o];
    lgl[tid] = logf(fmaxf(bdpack[o + 1], 1e-30f));
  }
  __syncthreads();
  if (tid < 64) {
    float s = 0.f;
    for (int j = 0; j <= tid; ++j) s += lgl[j];
    bl[tid] = s;
    Bvec[(size_t)ch * 64 + tid] = expf(s);
  }
  __syncthreads();

  // KK^T -> A (f32 LDS, strict lower, scaled); QK^T -> P (bf16 global)
  {
    f32x4 akk[4] = {}, aqk[4] = {};
#pragma unroll
    for (int ks = 0; ks < 4; ++ks) {
      bf16x8 kaF = *(const bf16x8*)(Kl + (w * 16 + r15) * 128 + ks * 32 + kb * 8);
      bf16x8 qaF = *(const bf16x8*)(Ql + (w * 16 + r15) * 128 + ks * 32 + kb * 8);
#pragma unroll
      for (int n = 0; n < 4; ++n) {
        bf16x8 bF = *(const bf16x8*)(Kl + (n * 16 + r15) * 128 + ks * 32 + kb * 8);
        akk[n] = __builtin_amdgcn_mfma_f32_16x16x32_bf16(kaF, bF, akk[n], 0, 0, 0);
        aqk[n] = __builtin_amdgcn_mfma_f32_16x16x32_bf16(qaF, bF, aqk[n], 0, 0, 0);
      }
    }
#pragma unroll
    for (int n = 0; n < 4; ++n)
#pragma unroll
      for (int r = 0; r < 4; ++r) {
        int i = w * 16 + kb * 4 + r;
        int j = n * 16 + r15;
        float e = expf(bl[i] - bl[j]);  // only used when j<=i (<=0 exponent)
        Af[i * 64 + j] = (j < i) ? betal[i] * e * akk[n][r] : 0.f;
        u16 pv = (j <= i) ? f2bf(e * aqk[n][r]) : (u16)0;
        Pg[(size_t)ch * 4096 + i * 64 + j] = pv;
      }
  }
  // KtT[d][j] = exp(b63-b_j) * K[j][d]  (bf16 global [128][64])
  float b63 = bl[63];
  for (int m = 0; m < 32; ++m) {
    int idx = tid * 32 + m;
    int d = idx >> 6, j = idx & 63;
    float v = bf2f(Kl[j * 128 + d]) * expf(b63 - bl[j]);
    KtTg[(size_t)ch * 8192 + idx] = f2bf(v);
  }
  __syncthreads();
  // T = I
#pragma unroll
  for (int m = 0; m < 16; ++m) Tf[tid * 16 + m] = 0.f;
  __syncthreads();
  if (tid < 64) Tf[tid * 65] = 1.f;
  __syncthreads();
  // forward substitution: wave w owns 16 columns, 4-way k-partials per column
  {
    int ccol = w * 16 + r15;
    int p = kb;
    for (int i = 1; i < 64; ++i) {
      float part = 0.f;
      for (int j = p; j < i; j += 4) part += Af[i * 64 + j] * Tf[j * 64 + ccol];
      part += __shfl_xor(part, 16, 64);
      part += __shfl_xor(part, 32, 64);
      if (p == 0) Tf[i * 64 + ccol] = ((ccol == i) ? 1.f : 0.f) - part;
    }
  }
  __syncthreads();
#pragma unroll
  for (int m = 0; m < 16; ++m) {
    int idx = tid * 16 + m;
    Tg[(size_t)ch * 4096 + idx] = f2bf(Tf[idx]);
  }
}

__global__ __launch_bounds__(512) void chunk_scan_kernel(
    const u16* __restrict__ qkvc, const float* __restrict__ bdpack,
    const u16* __restrict__ Tg, const u16* __restrict__ Pg,
    const u16* __restrict__ KtTg, const float* __restrict__ Bvec,
    u16* __restrict__ obf) {
  __shared__ __align__(16) u16 Kl[64 * 128];
  __shared__ __align__(16) u16 Ql[64 * 128];
  __shared__ __align__(16) u16 KtTl[128 * 64];
  __shared__ __align__(16) u16 Tl[64 * 64];
  __shared__ __align__(16) u16 Pl[64 * 64];
  __shared__ __align__(16) u16 Vl[64 * 32];
  __shared__ __align__(16) u16 St[32 * 128];
  __shared__ __align__(16) u16 rhsT[32 * 64];
  __shared__ __align__(16) u16 dT[32 * 64];
  __shared__ float betal[64], Gl[64];

  int tid = threadIdx.x;
  int w = tid >> 6, l = tid & 63;
  int r15 = l & 15, kb = l >> 4;
  int dvc = blockIdx.x, bh = blockIdx.y;
  int b = bh >> 5, h = bh & 31, hk = h >> 1;
  int a = w >> 1, bcol = w & 1;  // [64x32]-output tile: rows a*16.., cols bcol*16..

  for (int m = tid; m < 32 * 128; m += 512) St[m] = 0;
  f32x4 sAcc0 = {}, sAcc1 = {};
  __syncthreads();

  for (int c = 0; c < 16; ++c) {
    size_t tok0 = (size_t)b * 1024 + c * 64;
    int ch = bh * 16 + c;
    // ---- stage ----
#pragma unroll
    for (int rep = 0; rep < 2; ++rep) {
      int gid = w * 128 + rep * 64 + l;
      int row = gid >> 4, seg = gid & 15;
      const u16* srcq = qkvc + (tok0 + row) * CONVC + hk * 128 + seg * 8;
      async16(srcq, Ql + gid * 8);
      async16(srcq + KEYDIM, Kl + gid * 8);
      async16(KtTg + (size_t)ch * 8192 + gid * 8, KtTl + gid * 8);
    }
    {
      int gid = w * 64 + l;
      async16(Tg + (size_t)ch * 4096 + gid * 8, Tl + gid * 8);
      async16(Pg + (size_t)ch * 4096 + gid * 8, Pl + gid * 8);
    }
    if (w < 4) {
      int gid = w * 64 + l;  // 256 granules
      int row = gid >> 2, seg = gid & 3;
      async16(qkvc + (tok0 + row) * CONVC + 2 * KEYDIM + h * 128 + dvc * 32 + seg * 8,
              Vl + gid * 8);
    }
    if (tid < 64) {
      betal[tid] = bdpack[((size_t)bh * 1024 + c * 64 + tid) * 2];
      Gl[tid] = Bvec[(size_t)ch * 64 + tid];
    }
    __syncthreads();

    // ---- KS0 = K@S0, QS0 = Q@S0 ----
    f32x4 aKS = {}, aQS = {};
#pragma unroll
    for (int ks = 0; ks < 4; ++ks) {
      bf16x8 bF = *(const bf16x8*)(St + (bcol * 16 + r15) * 128 + ks * 32 + kb * 8);
      bf16x8 kF = *(const bf16x8*)(Kl + (a * 16 + r15) * 128 + ks * 32 + kb * 8);
      bf16x8 qF = *(const bf16x8*)(Ql + (a * 16 + r15) * 128 + ks * 32 + kb * 8);
      aKS = __builtin_amdgcn_mfma_f32_16x16x32_bf16(kF, bF, aKS, 0, 0, 0);
      aQS = __builtin_amdgcn_mfma_f32_16x16x32_bf16(qF, bF, aQS, 0, 0, 0);
    }
    // ---- rhsT[dv][i] = beta_i (v - B_i * KS0) ----
    {
      int i0 = a * 16 + kb * 4;
      int dv = bcol * 16 + r15;
      u16x4 st;
#pragma unroll
      for (int r = 0; r < 4; ++r) {
        int i = i0 + r;
        float v = bf2f(Vl[i * 32 + dv]);
        st[r] = f2bf(betal[i] * (v - Gl[i] * aKS[r]));
      }
      *(u16x4*)(rhsT + dv * 64 + i0) = st;
    }
    __syncthreads();
    // ---- delta = T @ rhs ----
    f32x4 aD = {};
#pragma unroll
    for (int ks = 0; ks < 2; ++ks) {
      bf16x8 aF = *(const bf16x8*)(Tl + (a * 16 + r15) * 64 + ks * 32 + kb * 8);
      bf16x8 bF = *(const bf16x8*)(rhsT + (bcol * 16 + r15) * 64 + ks * 32 + kb * 8);
      aD = __builtin_amdgcn_mfma_f32_16x16x32_bf16(aF, bF, aD, 0, 0, 0);
    }
    {
      int i0 = a * 16 + kb * 4;
      int dv = bcol * 16 + r15;
      u16x4 st;
#pragma unroll
      for (int r = 0; r < 4; ++r) st[r] = f2bf(aD[r]);
      *(u16x4*)(dT + dv * 64 + i0) = st;
    }
    __syncthreads();
    // ---- O = B.*QS0 + P @ delta -> global ----
    f32x4 aO = {};
#pragma unroll
    for (int ks = 0; ks < 2; ++ks) {
      bf16x8 aF = *(const bf16x8*)(Pl + (a * 16 + r15) * 64 + ks * 32 + kb * 8);
      bf16x8 bF = *(const bf16x8*)(dT + (bcol * 16 + r15) * 64 + ks * 32 + kb * 8);
      aO = __builtin_amdgcn_mfma_f32_16x16x32_bf16(aF, bF, aO, 0, 0, 0);
    }
    {
      int i0 = a * 16 + kb * 4;
      int dv = bcol * 16 + r15;
#pragma unroll
      for (int r = 0; r < 4; ++r) {
        int i = i0 + r;
        float o = aO[r] + Gl[i] * aQS[r];
        obf[(tok0 + i) * VALDIM + h * 128 + dvc * 32 + dv] = f2bf(o);
      }
    }
    // ---- state update: S = B63*S + KtT @ delta ----
    float gL = Gl[63];
#pragma unroll
    for (int r = 0; r < 4; ++r) { sAcc0[r] *= gL; sAcc1[r] *= gL; }
#pragma unroll
    for (int ks = 0; ks < 2; ++ks) {
      bf16x8 aF = *(const bf16x8*)(KtTl + (w * 16 + r15) * 64 + ks * 32 + kb * 8);
      bf16x8 b0 = *(const bf16x8*)(dT + r15 * 64 + ks * 32 + kb * 8);
      bf16x8 b1 = *(const bf16x8*)(dT + (16 + r15) * 64 + ks * 32 + kb * 8);
      sAcc0 = __builtin_amdgcn_mfma_f32_16x16x32_bf16(aF, b0, sAcc0, 0, 0, 0);
      sAcc1 = __builtin_amdgcn_mfma_f32_16x16x32_bf16(aF, b1, sAcc1, 0, 0, 0);
    }
#pragma unroll
    for (int r = 0; r < 4; ++r) {
      int dk = w * 16 + kb * 4 + r;
      St[r15 * 128 + dk] = f2bf(sAcc0[r]);
      St[(16 + r15) * 128 + dk] = f2bf(sAcc1[r]);
    }
    __syncthreads();
  }
}

// -------- gate (silu(z)) + per-head RMSNorm, in-place over z ----------------
__global__ __launch_bounds__(256) void gatenorm_kernel(
    const u16* __restrict__ obf, u16* __restrict__ zb,
    const float* __restrict__ norm_w) {
  int wid = blockIdx.x * 4 + (threadIdx.x >> 6);
  int l = threadIdx.x & 63;
  int tok = wid >> 5, h = wid & 31;
  const u16* op = obf + (size_t)tok * VALDIM + h * 128 + l * 2;
  u16* zp = zb + (size_t)tok * VALDIM + h * 128 + l * 2;
  float o0 = bf2f(op[0]), o1 = bf2f(op[1]);
  float z0 = bf2f(zp[0]), z1 = bf2f(zp[1]);
  float g0 = o0 * siluf(z0);
  float g1 = o1 * siluf(z1);
  float ss = g0 * g0 + g1 * g1;
#pragma unroll
  for (int m = 1; m < 64; m <<= 1) ss += __shfl_xor(ss, m, 64);
  float sc = rsqrtf(ss * (1.f / 128.f) + 1e-6f);
  int e = l * 2;
  *(u32*)zp = pack2(g0 * sc * norm_w[e], g1 * sc * norm_w[e + 1]);
}

// -------- m = silu(g) * u -> bf16 (in place over u) -------------------------
__global__ __launch_bounds__(256) void mact_kernel(const u16* __restrict__ g,
                                                   u16* __restrict__ u) {
  size_t i = ((size_t)blockIdx.x * 256 + threadIdx.x) * 8;
  bf16x8 gv = *(const bf16x8*)(g + i);
  bf16x8 uv = *(const bf16x8*)(u + i);
  u32x4 st;
#pragma unroll
  for (int j = 0; j < 4; ++j) {
    float a0 = siluf(bf2f((u16)gv[2 * j])) * bf2f((u16)uv[2 * j]);
    float a1 = siluf(bf2f((u16)gv[2 * j + 1])) * bf2f((u16)uv[2 * j + 1]);
    st[j] = pack2(a0, a1);
  }
  *(u32x4*)(u + i) = st;
}

// -------- diagnostic: encode ws_size into d_out[0] --------------------------
__global__ void diag_kernel(float* out, float val) { out[0] = val; }

extern "C" void kernel_launch(void* const* d_in, const int* in_sizes, int n_in,
                              void* d_out, int out_size, void* d_ws,
                              size_t ws_size, hipStream_t stream) {
  const float* hidden = (const float*)d_in[1];
  const float* residual = (const float*)d_in[2];
  const float* ln_in_w = (const float*)d_in[3];
  const float* ln_post_w = (const float*)d_in[4];
  const float* Wqkvz = (const float*)d_in[5];
  const float* Wba = (const float*)d_in[6];
  const float* conv_w = (const float*)d_in[7];
  const float* A_log = (const float*)d_in[8];
  const float* dt_bias = (const float*)d_in[9];
  const float* norm_w = (const float*)d_in[10];
  const float* Wout = (const float*)d_in[11];
  const float* Wgate = (const float*)d_in[12];
  const float* Wup = (const float*)d_in[13];
  const float* Wdown = (const float*)d_in[14];

  char* ws = (char*)d_ws;
  size_t off = 0;
  auto alloc = [&](size_t n) {
    char* p = ws + off;
    off = (off + n + 255) & ~(size_t)255;
    return p;
  };
  u16* wslot = (u16*)alloc((size_t)INTER * DMODEL * 2);       // 33.55 MB
  u16* hb = (u16*)alloc((size_t)BT * DMODEL * 2);             //  8.39 MB
  u16* qkvb = (u16*)alloc((size_t)BT * CONVC * 2);            // 33.55 MB
  u16* zb = (u16*)alloc((size_t)BT * VALDIM * 2);             // 16.78 MB
  u16* qkvc = (u16*)alloc((size_t)BT * CONVC * 2);            // 33.55 MB
  float* ba = (float*)alloc((size_t)BT * 64 * 4);             //  0.52 MB
  float* bdpack = (float*)alloc((size_t)64 * 1024 * 2 * 4);   //  0.52 MB
  u16* obf = (u16*)alloc((size_t)BT * VALDIM * 2);            // 16.78 MB
  if (off > ws_size) {                                        // ~143.7 MB total
    diag_kernel<<<1, 1, 0, stream>>>((float*)d_out, (float)(ws_size >> 20));
    return;
  }

  float* res1 = (float*)d_out;                        // part1 (dead before out)
  float* attn = (float*)d_out + (size_t)BT * DMODEL;  // part2
  float* res2 = attn;                                 // in-place
  u16* h2b = hb;                                      // hb dead after GEMM1/ba
  u16* gbuf = qkvc;                                   // qkvc dead after scan
  u16* ubuf = qkvb;                                   // qkvb dead after conv
  u16* mbuf = qkvb;                                   // in-place over u
  float* outp = (float*)d_out;                        // final (res1 dead)

  // chunked-scan prep outputs live in dead qkvb (exact fit) + ba regions
  u16* Tg = qkvb;                                     // 1024 x 4096 u16
  u16* Pg = qkvb + (size_t)1024 * 4096;               // 1024 x 4096 u16
  u16* KtTg = qkvb + (size_t)2 * 1024 * 4096;         // 1024 x 8192 u16
  float* Bvec = ba;                                   // 1024 x 64 f32

  dim3 blk(256);

  // 1. res1 = hidden+residual; hb = rmsnorm(res1)
  resnorm_kernel<<<BT, blk, 0, stream>>>(hidden, residual, ln_in_w, res1, hb);

  // 2. qkv-slice GEMM: qkvb = hb @ Wqkvz[:, :8192]
  convert_transpose<<<dim3(CONVC / 32, DMODEL / 32), blk, 0, stream>>>(
      Wqkvz, QKVZ_N, wslot, DMODEL, CONVC);
  gemm_kernel<1><<<dim3(CONVC / 128, BT / 128), blk, 0, stream>>>(
      hb, wslot, qkvb, BT, CONVC, DMODEL);

  // 3. z-slice GEMM: zb = hb @ Wqkvz[:, 8192:]
  convert_transpose<<<dim3(VALDIM / 32, DMODEL / 32), blk, 0, stream>>>(
      Wqkvz + CONVC, QKVZ_N, wslot, DMODEL, VALDIM);
  gemm_kernel<1><<<dim3(VALDIM / 128, BT / 128), blk, 0, stream>>>(
      hb, wslot, zb, BT, VALDIM, DMODEL);

  // 4. ba = hb @ Wba
  ba_gemm_kernel<<<BT, blk, 0, stream>>>(hb, Wba, ba);

  // 5-7. conv+silu, l2norm(q,k), beta/decay (packed per-head layout)
  conv_silu_kernel<<<BT * 2048 / 256, blk, 0, stream>>>(qkvb, conv_w, qkvc);
  l2norm_kernel<<<BT * 32 / 4, blk, 0, stream>>>(qkvc);
  betadecay_kernel<<<BT * HV / 256, blk, 0, stream>>>(ba, A_log, dt_bias,
                                                      bdpack);

  // 8. chunked gated delta rule scan (prep parallel, then sequential-in-chunk)
  prep_kernel<<<dim3(16, 64), blk, 0, stream>>>(qkvc, bdpack, Tg, Pg, KtTg,
                                                Bvec);
  chunk_scan_kernel<<<dim3(4, 64), dim3(512), 0, stream>>>(
      qkvc, bdpack, Tg, Pg, KtTg, Bvec, obf);

  // 9. gate + per-head RMSNorm (in place over zb)
  gatenorm_kernel<<<BT * HV / 4, blk, 0, stream>>>(obf, zb, norm_w);

  // 10. attn = og @ Wout  (f32, into d_out part2)
  convert_transpose<<<dim3(DMODEL / 32, VALDIM / 32), blk, 0, stream>>>(
      Wout, DMODEL, wslot, VALDIM, DMODEL);
  gemm_kernel<0><<<dim3(DMODEL / 128, BT / 128), blk, 0, stream>>>(
      zb, wslot, attn, BT, DMODEL, VALDIM);

  // 11. res2 = attn + res1 (in place, part2); h2b = rmsnorm(res2)
  resnorm_kernel<<<BT, blk, 0, stream>>>(attn, res1, ln_post_w, res2, h2b);

  // 12-13. gate & up GEMMs (bf16 outs)
  convert_transpose<<<dim3(INTER / 32, DMODEL / 32), blk, 0, stream>>>(
      Wgate, INTER, wslot, DMODEL, INTER);
  gemm_kernel<1><<<dim3(INTER / 128, BT / 128), blk, 0, stream>>>(
      h2b, wslot, gbuf, BT, INTER, DMODEL);
  convert_transpose<<<dim3(INTER / 32, DMODEL / 32), blk, 0, stream>>>(
      Wup, INTER, wslot, DMODEL, INTER);
  gemm_kernel<1><<<dim3(INTER / 128, BT / 128), blk, 0, stream>>>(
      h2b, wslot, ubuf, BT, INTER, DMODEL);

  // 14. m = silu(g)*u (in place over u)
  mact_kernel<<<BT * INTER / 8 / 256, blk, 0, stream>>>(gbuf, ubuf);

  // 15. out = m @ Wdown (f32, d_out part1)
  convert_transpose<<<dim3(DMODEL / 32, INTER / 32), blk, 0, stream>>>(
      Wdown, DMODEL, wslot, INTER, DMODEL);
  gemm_kernel<0><<<dim3(DMODEL / 128, BT / 128), blk, 0, stream>>>(
      mbuf, wslot, outp, BT, DMODEL, INTER);
}

// Round 7
// 976.991 us; speedup vs baseline: 1.6583x; 1.0601x over previous
//
#include <hip/hip_runtime.h>
#include <hip/hip_bf16.h>

typedef unsigned short u16;
typedef unsigned int u32;
typedef float f32x4 __attribute__((ext_vector_type(4)));
typedef short bf16x8 __attribute__((ext_vector_type(8)));
typedef unsigned short u16x4 __attribute__((ext_vector_type(4)));
typedef unsigned int u32x2 __attribute__((ext_vector_type(2)));
typedef unsigned int u32x4 __attribute__((ext_vector_type(4)));

#define BT 2048            // B*T
#define DMODEL 2048
#define HV 32
#define DK 128
#define KEYDIM 2048
#define VALDIM 4096
#define QKVZ_N 12288
#define CONVC 8192         // q,k,v channels
#define INTER 8192

__device__ __forceinline__ float bf2f(u16 v) {
  u32 u = ((u32)v) << 16;
  return __builtin_bit_cast(float, u);
}
__device__ __forceinline__ u16 f2bf(float f) {
  u32 u = __builtin_bit_cast(u32, f);
  u32 r = (u + 0x7fffu + ((u >> 16) & 1u)) >> 16;
  return (u16)r;
}
__device__ __forceinline__ u32 pack2(float a, float b) {
  return (u32)f2bf(a) | ((u32)f2bf(b) << 16);
}
__device__ __forceinline__ float siluf(float x) {
  return x / (1.f + expf(-x));
}

// -------- weight convert+transpose: W[K,N] f32 (row stride ldw) -> Wt[N,K] bf16
__global__ __launch_bounds__(256) void convert_transpose(
    const float* __restrict__ W, int ldw, u16* __restrict__ Wt, int K, int N) {
  __shared__ float tile[32][33];
  int n0 = blockIdx.x * 32, k0 = blockIdx.y * 32;
  int tx = threadIdx.x & 31, ty = threadIdx.x >> 5;  // ty 0..7
#pragma unroll
  for (int i = 0; i < 4; ++i) {
    int kk = ty + i * 8;
    tile[kk][tx] = W[(size_t)(k0 + kk) * ldw + n0 + tx];
  }
  __syncthreads();
#pragma unroll
  for (int i = 0; i < 4; ++i) {
    int nn = ty + i * 8;
    Wt[(size_t)(n0 + nn) * K + k0 + tx] = f2bf(tile[tx][nn]);
  }
}

// -------- fused residual add + gemma RMSNorm (a+b -> resout f32, norm -> bf16)
__global__ __launch_bounds__(256) void resnorm_kernel(
    const float* __restrict__ a, const float* __restrict__ b,
    const float* __restrict__ w, float* __restrict__ resout,
    u16* __restrict__ hb) {
  int tok = blockIdx.x, t = threadIdx.x;
  const float* ap = a + (size_t)tok * DMODEL + t * 8;
  const float* bp = b + (size_t)tok * DMODEL + t * 8;
  f32x4 x0 = *(const f32x4*)ap + *(const f32x4*)bp;
  f32x4 x1 = *(const f32x4*)(ap + 4) + *(const f32x4*)(bp + 4);
  *(f32x4*)(resout + (size_t)tok * DMODEL + t * 8) = x0;
  *(f32x4*)(resout + (size_t)tok * DMODEL + t * 8 + 4) = x1;
  float ss = 0.f;
#pragma unroll
  for (int j = 0; j < 4; ++j) ss += x0[j] * x0[j] + x1[j] * x1[j];
#pragma unroll
  for (int m = 1; m < 64; m <<= 1) ss += __shfl_xor(ss, m, 64);
  __shared__ float red[4];
  if ((t & 63) == 0) red[t >> 6] = ss;
  __syncthreads();
  ss = red[0] + red[1] + red[2] + red[3];
  float sc = rsqrtf(ss * (1.f / (float)DMODEL) + 1e-6f);
  const float* wp = w + t * 8;
  float y[8];
#pragma unroll
  for (int j = 0; j < 4; ++j) {
    y[j] = x0[j] * sc * (1.f + wp[j]);
    y[4 + j] = x1[j] * sc * (1.f + wp[4 + j]);
  }
  u32x4 st;
  st[0] = pack2(y[0], y[1]);
  st[1] = pack2(y[2], y[3]);
  st[2] = pack2(y[4], y[5]);
  st[3] = pack2(y[6], y[7]);
  *(u32x4*)(hb + (size_t)tok * DMODEL + t * 8) = st;
}

// -------- bf16 MFMA GEMM: C[M,N] = A[M,K]_bf16 * Bt[N,K]^T ------------------
// OUT: 0=f32 out, 1=bf16 out, 2=bf16 out of silu(Aux)*acc (fused SwiGLU).
// 2-phase pipeline: double-buffered LDS, prefetch next K-tile before compute.
// Rasterization: bijective XCD chunking + group-major (GRP=4) for L2 reuse.
__device__ __forceinline__ void async16(const void* g, void* l) {
  __builtin_amdgcn_global_load_lds(
      (const __attribute__((address_space(1))) u32*)g,
      (__attribute__((address_space(3))) u32*)l, 16, 0, 0);
}

template <int OUT>
__global__ __launch_bounds__(256) void gemm_kernel(
    const u16* __restrict__ A, const u16* __restrict__ Bt,
    void* __restrict__ Cv, const u16* __restrict__ Aux, int M, int N, int K) {
  __shared__ __align__(16) u16 Al[2][128 * 32];
  __shared__ __align__(16) u16 Bl[2][128 * 32];
  int tid = threadIdx.x;
  int w = tid >> 6, l = tid & 63;
  int wr = w >> 1, wc = w & 1;
  int r15 = l & 15, kb = l >> 4;

  // ---- rasterization: XCD chunk (nwg%8==0 for all our grids) + group-major
  int nbx = gridDim.x, nby = gridDim.y;
  int bid = blockIdx.y * nbx + blockIdx.x;
  int nwg = nbx * nby;
  int cpx = nwg >> 3;
  int wg = (bid & 7) * cpx + (bid >> 3);
  const int GRP = 4;  // n-tiles per group (nbx % 4 == 0 in all launches)
  int span = GRP * nby;
  int grpId = wg / span;
  int rem = wg - grpId * span;
  int n0 = (grpId * GRP + (rem % GRP)) * 128;
  int m0 = (rem / GRP) * 128;

  f32x4 acc[4][4] = {};

  auto stage = [&](int buf, int kt) {
#pragma unroll
    for (int c = 0; c < 2; ++c) {
      int gid = w * 128 + c * 64 + l;          // 16B granule id in tile
      int row = gid >> 2;
      int g = (gid & 3) ^ ((row >> 1) & 3);    // pre-swizzled source granule
      async16(A + (size_t)(m0 + row) * K + kt + g * 8, Al[buf] + gid * 8);
      async16(Bt + (size_t)(n0 + row) * K + kt + g * 8, Bl[buf] + gid * 8);
    }
  };

  stage(0, 0);
  __syncthreads();
  int cur = 0;
  for (int kt = 0; kt < K; kt += 32) {
    if (kt + 32 < K) stage(cur ^ 1, kt + 32);  // prefetch overlaps MFMA below
    bf16x8 aF[4], bF[4];
#pragma unroll
    for (int m = 0; m < 4; ++m) {
      int row = wr * 64 + m * 16 + r15;
      aF[m] = *(const bf16x8*)(Al[cur] + row * 32 + (kb ^ ((row >> 1) & 3)) * 8);
    }
#pragma unroll
    for (int n = 0; n < 4; ++n) {
      int row = wc * 64 + n * 16 + r15;
      bF[n] = *(const bf16x8*)(Bl[cur] + row * 32 + (kb ^ ((row >> 1) & 3)) * 8);
    }
#pragma unroll
    for (int m = 0; m < 4; ++m)
#pragma unroll
      for (int n = 0; n < 4; ++n)
        acc[m][n] = __builtin_amdgcn_mfma_f32_16x16x32_bf16(aF[m], bF[n],
                                                            acc[m][n], 0, 0, 0);
    __syncthreads();  // drains vmcnt (next tile ready) + lgkm; one barrier/iter
    cur ^= 1;
  }

#pragma unroll
  for (int m = 0; m < 4; ++m)
#pragma unroll
    for (int n = 0; n < 4; ++n) {
      size_t base = (size_t)(m0 + wr * 64 + m * 16 + kb * 4) * N +
                    (n0 + wc * 64 + n * 16 + r15);
#pragma unroll
      for (int r = 0; r < 4; ++r) {
        size_t idx = base + (size_t)r * N;
        if (OUT == 0)
          ((float*)Cv)[idx] = acc[m][n][r];
        else if (OUT == 1)
          ((u16*)Cv)[idx] = f2bf(acc[m][n][r]);
        else
          ((u16*)Cv)[idx] = f2bf(siluf(bf2f(Aux[idx])) * acc[m][n][r]);
      }
    }
}

// -------- ba = hb(bf16) @ Wba(f32 [2048,64]) --------------------------------
__global__ __launch_bounds__(256) void ba_gemm_kernel(
    const u16* __restrict__ hb, const float* __restrict__ Wba,
    float* __restrict__ ba) {
  int m = blockIdx.x;
  int t = threadIdx.x;
  int n = t & 63, kq = t >> 6;
  const u16* a = hb + (size_t)m * DMODEL + kq * 512;
  const float* wp = Wba + (size_t)kq * 512 * 64 + n;
  float sum = 0.f;
  for (int i = 0; i < 512; ++i)
    sum += bf2f(a[i]) * wp[(size_t)i * 64];
  __shared__ float red[256];
  red[t] = sum;
  __syncthreads();
  if (t < 64)
    ba[(size_t)m * 64 + t] = red[t] + red[t + 64] + red[t + 128] + red[t + 192];
}

// -------- causal depthwise conv (K=4) + SiLU, bf16 in/out -------------------
__global__ __launch_bounds__(256) void conv_silu_kernel(
    const u16* __restrict__ qkvb, const float* __restrict__ conv_w,
    u16* __restrict__ qkv) {
  int gid = blockIdx.x * 256 + threadIdx.x;  // BT * 2048 threads
  int c4 = (gid & 2047) * 4;
  int bt = gid >> 11;
  int b = bt >> 10, tt = bt & 1023;
  f32x4 wv[4];
#pragma unroll
  for (int j = 0; j < 4; ++j) wv[j] = *(const f32x4*)(conv_w + (c4 + j) * 4);
  float acc[4] = {0.f, 0.f, 0.f, 0.f};
#pragma unroll
  for (int i = 0; i < 4; ++i) {
    int ts = tt - 3 + i;
    if (ts >= 0) {
      u16x4 x = *(const u16x4*)(qkvb + (size_t)(b * 1024 + ts) * CONVC + c4);
#pragma unroll
      for (int j = 0; j < 4; ++j) acc[j] += bf2f(x[j]) * wv[j][i];
    }
  }
  u32x2 st;
  st[0] = pack2(siluf(acc[0]), siluf(acc[1]));
  st[1] = pack2(siluf(acc[2]), siluf(acc[3]));
  *(u32x2*)(qkv + (size_t)bt * CONVC + c4) = st;
}

// -------- l2 norm of q,k heads in place (bf16), q also * DK^-0.5 ------------
__global__ __launch_bounds__(256) void l2norm_kernel(u16* __restrict__ qkv) {
  int wid = blockIdx.x * 4 + (threadIdx.x >> 6);
  int l = threadIdx.x & 63;
  int tok = wid >> 5, slot = wid & 31;  // slot<16: q head, else k head
  u16* p = qkv + (size_t)tok * CONVC + slot * 128 + l * 2;
  float x0 = bf2f(p[0]), x1 = bf2f(p[1]);
  float ss = x0 * x0 + x1 * x1;
#pragma unroll
  for (int m = 1; m < 64; m <<= 1) ss += __shfl_xor(ss, m, 64);
  float sc = rsqrtf(ss + 1e-6f);
  if (slot < 16) sc *= 0.08838834764831845f;  // DK^-0.5
  *(u32*)p = pack2(x0 * sc, x1 * sc);
}

// -------- bd[(b*32+h)][t][2] = {sigmoid(bb), exp(-exp(A_log)*softplus)} -----
__global__ __launch_bounds__(256) void betadecay_kernel(
    const float* __restrict__ ba, const float* __restrict__ A_log,
    const float* __restrict__ dt_bias, float* __restrict__ bd) {
  int idx = blockIdx.x * 256 + threadIdx.x;  // BT*HV
  int h = idx & 31;
  int tok = idx >> 5;
  int b = tok >> 10, tt = tok & 1023;
  float bb = ba[(size_t)tok * 64 + h];
  float aa = ba[(size_t)tok * 64 + 32 + h];
  float bet = 1.f / (1.f + expf(-bb));
  float x = aa + dt_bias[h];
  float sp = (x > 20.f) ? x : log1pf(expf(x));
  float dec = expf(-expf(A_log[h]) * sp);
  size_t o = (((size_t)(b * 32 + h)) * 1024 + tt) * 2;
  bd[o] = bet;
  bd[o + 1] = dec;
}

// ======================= chunked delta-rule scan ============================
__global__ __launch_bounds__(256) void prep_kernel(
    const u16* __restrict__ qkvc, const float* __restrict__ bdpack,
    u16* __restrict__ Tg, u16* __restrict__ Pg, u16* __restrict__ KtTg,
    float* __restrict__ Bvec) {
  __shared__ __align__(16) u16 Kl[64 * 128];
  __shared__ __align__(16) u16 Ql[64 * 128];
  __shared__ __align__(16) float Af[64 * 64];
  __shared__ __align__(16) float Tf[64 * 64];
  __shared__ float lgl[64], bl[64], betal[64];
  int tid = threadIdx.x;
  int w = tid >> 6, l = tid & 63;
  int r15 = l & 15, kb = l >> 4;
  int c = blockIdx.x, bh = blockIdx.y;
  int b = bh >> 5, h = bh & 31, hk = h >> 1;
  size_t tok0 = (size_t)b * 1024 + c * 64;
  int ch = bh * 16 + c;  // chunk-head index

  // stage K, Q tiles [64][128] bf16
#pragma unroll
  for (int rep = 0; rep < 4; ++rep) {
    int gid = w * 256 + rep * 64 + l;
    int row = gid >> 4, seg = gid & 15;
    const u16* srcq = qkvc + (tok0 + row) * CONVC + hk * 128 + seg * 8;
    async16(srcq, Ql + gid * 8);
    async16(srcq + KEYDIM, Kl + gid * 8);
  }
  if (tid < 64) {
    size_t o = ((size_t)bh * 1024 + c * 64 + tid) * 2;
    betal[tid] = bdpack[o];
    lgl[tid] = logf(fmaxf(bdpack[o + 1], 1e-30f));
  }
  __syncthreads();
  if (tid < 64) {
    float s = 0.f;
    for (int j = 0; j <= tid; ++j) s += lgl[j];
    bl[tid] = s;
    Bvec[(size_t)ch * 64 + tid] = expf(s);
  }
  __syncthreads();

  // KK^T -> A (f32 LDS, strict lower, scaled); QK^T -> P (bf16 global)
  {
    f32x4 akk[4] = {}, aqk[4] = {};
#pragma unroll
    for (int ks = 0; ks < 4; ++ks) {
      bf16x8 kaF = *(const bf16x8*)(Kl + (w * 16 + r15) * 128 + ks * 32 + kb * 8);
      bf16x8 qaF = *(const bf16x8*)(Ql + (w * 16 + r15) * 128 + ks * 32 + kb * 8);
#pragma unroll
      for (int n = 0; n < 4; ++n) {
        bf16x8 bF = *(const bf16x8*)(Kl + (n * 16 + r15) * 128 + ks * 32 + kb * 8);
        akk[n] = __builtin_amdgcn_mfma_f32_16x16x32_bf16(kaF, bF, akk[n], 0, 0, 0);
        aqk[n] = __builtin_amdgcn_mfma_f32_16x16x32_bf16(qaF, bF, aqk[n], 0, 0, 0);
      }
    }
#pragma unroll
    for (int n = 0; n < 4; ++n)
#pragma unroll
      for (int r = 0; r < 4; ++r) {
        int i = w * 16 + kb * 4 + r;
        int j = n * 16 + r15;
        float e = expf(bl[i] - bl[j]);  // only used when j<=i (<=0 exponent)
        Af[i * 64 + j] = (j < i) ? betal[i] * e * akk[n][r] : 0.f;
        u16 pv = (j <= i) ? f2bf(e * aqk[n][r]) : (u16)0;
        Pg[(size_t)ch * 4096 + i * 64 + j] = pv;
      }
  }
  // KtT[d][j] = exp(b63-b_j) * K[j][d]  (bf16 global [128][64])
  float b63 = bl[63];
  for (int m = 0; m < 32; ++m) {
    int idx = tid * 32 + m;
    int d = idx >> 6, j = idx & 63;
    float v = bf2f(Kl[j * 128 + d]) * expf(b63 - bl[j]);
    KtTg[(size_t)ch * 8192 + idx] = f2bf(v);
  }
  __syncthreads();
  // T = I
#pragma unroll
  for (int m = 0; m < 16; ++m) Tf[tid * 16 + m] = 0.f;
  __syncthreads();
  if (tid < 64) Tf[tid * 65] = 1.f;
  __syncthreads();
  // forward substitution: wave w owns 16 columns, 4-way k-partials per column
  {
    int ccol = w * 16 + r15;
    int p = kb;
    for (int i = 1; i < 64; ++i) {
      float part = 0.f;
      for (int j = p; j < i; j += 4) part += Af[i * 64 + j] * Tf[j * 64 + ccol];
      part += __shfl_xor(part, 16, 64);
      part += __shfl_xor(part, 32, 64);
      if (p == 0) Tf[i * 64 + ccol] = ((ccol == i) ? 1.f : 0.f) - part;
    }
  }
  __syncthreads();
#pragma unroll
  for (int m = 0; m < 16; ++m) {
    int idx = tid * 16 + m;
    Tg[(size_t)ch * 4096 + idx] = f2bf(Tf[idx]);
  }
}

__global__ __launch_bounds__(512) void chunk_scan_kernel(
    const u16* __restrict__ qkvc, const float* __restrict__ bdpack,
    const u16* __restrict__ Tg, const u16* __restrict__ Pg,
    const u16* __restrict__ KtTg, const float* __restrict__ Bvec,
    u16* __restrict__ obf) {
  __shared__ __align__(16) u16 Kl[64 * 128];
  __shared__ __align__(16) u16 Ql[64 * 128];
  __shared__ __align__(16) u16 KtTl[128 * 64];
  __shared__ __align__(16) u16 Tl[64 * 64];
  __shared__ __align__(16) u16 Pl[64 * 64];
  __shared__ __align__(16) u16 Vl[64 * 32];
  __shared__ __align__(16) u16 St[32 * 128];
  __shared__ __align__(16) u16 rhsT[32 * 64];
  __shared__ __align__(16) u16 dT[32 * 64];
  __shared__ float betal[64], Gl[64];

  int tid = threadIdx.x;
  int w = tid >> 6, l = tid & 63;
  int r15 = l & 15, kb = l >> 4;
  int dvc = blockIdx.x, bh = blockIdx.y;
  int b = bh >> 5, h = bh & 31, hk = h >> 1;
  int a = w >> 1, bcol = w & 1;  // [64x32]-output tile: rows a*16.., cols bcol*16..

  for (int m = tid; m < 32 * 128; m += 512) St[m] = 0;
  f32x4 sAcc0 = {}, sAcc1 = {};
  __syncthreads();

  for (int c = 0; c < 16; ++c) {
    size_t tok0 = (size_t)b * 1024 + c * 64;
    int ch = bh * 16 + c;
    // ---- stage ----
#pragma unroll
    for (int rep = 0; rep < 2; ++rep) {
      int gid = w * 128 + rep * 64 + l;
      int row = gid >> 4, seg = gid & 15;
      const u16* srcq = qkvc + (tok0 + row) * CONVC + hk * 128 + seg * 8;
      async16(srcq, Ql + gid * 8);
      async16(srcq + KEYDIM, Kl + gid * 8);
      async16(KtTg + (size_t)ch * 8192 + gid * 8, KtTl + gid * 8);
    }
    {
      int gid = w * 64 + l;
      async16(Tg + (size_t)ch * 4096 + gid * 8, Tl + gid * 8);
      async16(Pg + (size_t)ch * 4096 + gid * 8, Pl + gid * 8);
    }
    if (w < 4) {
      int gid = w * 64 + l;  // 256 granules
      int row = gid >> 2, seg = gid & 3;
      async16(qkvc + (tok0 + row) * CONVC + 2 * KEYDIM + h * 128 + dvc * 32 + seg * 8,
              Vl + gid * 8);
    }
    if (tid < 64) {
      betal[tid] = bdpack[((size_t)bh * 1024 + c * 64 + tid) * 2];
      Gl[tid] = Bvec[(size_t)ch * 64 + tid];
    }
    __syncthreads();

    // ---- KS0 = K@S0, QS0 = Q@S0 ----
    f32x4 aKS = {}, aQS = {};
#pragma unroll
    for (int ks = 0; ks < 4; ++ks) {
      bf16x8 bF = *(const bf16x8*)(St + (bcol * 16 + r15) * 128 + ks * 32 + kb * 8);
      bf16x8 kF = *(const bf16x8*)(Kl + (a * 16 + r15) * 128 + ks * 32 + kb * 8);
      bf16x8 qF = *(const bf16x8*)(Ql + (a * 16 + r15) * 128 + ks * 32 + kb * 8);
      aKS = __builtin_amdgcn_mfma_f32_16x16x32_bf16(kF, bF, aKS, 0, 0, 0);
      aQS = __builtin_amdgcn_mfma_f32_16x16x32_bf16(qF, bF, aQS, 0, 0, 0);
    }
    // ---- rhsT[dv][i] = beta_i (v - B_i * KS0) ----
    {
      int i0 = a * 16 + kb * 4;
      int dv = bcol * 16 + r15;
      u16x4 st;
#pragma unroll
      for (int r = 0; r < 4; ++r) {
        int i = i0 + r;
        float v = bf2f(Vl[i * 32 + dv]);
        st[r] = f2bf(betal[i] * (v - Gl[i] * aKS[r]));
      }
      *(u16x4*)(rhsT + dv * 64 + i0) = st;
    }
    __syncthreads();
    // ---- delta = T @ rhs ----
    f32x4 aD = {};
#pragma unroll
    for (int ks = 0; ks < 2; ++ks) {
      bf16x8 aF = *(const bf16x8*)(Tl + (a * 16 + r15) * 64 + ks * 32 + kb * 8);
      bf16x8 bF = *(const bf16x8*)(rhsT + (bcol * 16 + r15) * 64 + ks * 32 + kb * 8);
      aD = __builtin_amdgcn_mfma_f32_16x16x32_bf16(aF, bF, aD, 0, 0, 0);
    }
    {
      int i0 = a * 16 + kb * 4;
      int dv = bcol * 16 + r15;
      u16x4 st;
#pragma unroll
      for (int r = 0; r < 4; ++r) st[r] = f2bf(aD[r]);
      *(u16x4*)(dT + dv * 64 + i0) = st;
    }
    __syncthreads();
    // ---- O = B.*QS0 + P @ delta -> global ----
    f32x4 aO = {};
#pragma unroll
    for (int ks = 0; ks < 2; ++ks) {
      bf16x8 aF = *(const bf16x8*)(Pl + (a * 16 + r15) * 64 + ks * 32 + kb * 8);
      bf16x8 bF = *(const bf16x8*)(dT + (bcol * 16 + r15) * 64 + ks * 32 + kb * 8);
      aO = __builtin_amdgcn_mfma_f32_16x16x32_bf16(aF, bF, aO, 0, 0, 0);
    }
    {
      int i0 = a * 16 + kb * 4;
      int dv = bcol * 16 + r15;
#pragma unroll
      for (int r = 0; r < 4; ++r) {
        int i = i0 + r;
        float o = aO[r] + Gl[i] * aQS[r];
        obf[(tok0 + i) * VALDIM + h * 128 + dvc * 32 + dv] = f2bf(o);
      }
    }
    // ---- state update: S = B63*S + KtT @ delta ----
    float gL = Gl[63];
#pragma unroll
    for (int r = 0; r < 4; ++r) { sAcc0[r] *= gL; sAcc1[r] *= gL; }
#pragma unroll
    for (int ks = 0; ks < 2; ++ks) {
      bf16x8 aF = *(const bf16x8*)(KtTl + (w * 16 + r15) * 64 + ks * 32 + kb * 8);
      bf16x8 b0 = *(const bf16x8*)(dT + r15 * 64 + ks * 32 + kb * 8);
      bf16x8 b1 = *(const bf16x8*)(dT + (16 + r15) * 64 + ks * 32 + kb * 8);
      sAcc0 = __builtin_amdgcn_mfma_f32_16x16x32_bf16(aF, b0, sAcc0, 0, 0, 0);
      sAcc1 = __builtin_amdgcn_mfma_f32_16x16x32_bf16(aF, b1, sAcc1, 0, 0, 0);
    }
#pragma unroll
    for (int r = 0; r < 4; ++r) {
      int dk = w * 16 + kb * 4 + r;
      St[r15 * 128 + dk] = f2bf(sAcc0[r]);
      St[(16 + r15) * 128 + dk] = f2bf(sAcc1[r]);
    }
    __syncthreads();
  }
}

// -------- gate (silu(z)) + per-head RMSNorm, in-place over z ----------------
__global__ __launch_bounds__(256) void gatenorm_kernel(
    const u16* __restrict__ obf, u16* __restrict__ zb,
    const float* __restrict__ norm_w) {
  int wid = blockIdx.x * 4 + (threadIdx.x >> 6);
  int l = threadIdx.x & 63;
  int tok = wid >> 5, h = wid & 31;
  const u16* op = obf + (size_t)tok * VALDIM + h * 128 + l * 2;
  u16* zp = zb + (size_t)tok * VALDIM + h * 128 + l * 2;
  float o0 = bf2f(op[0]), o1 = bf2f(op[1]);
  float z0 = bf2f(zp[0]), z1 = bf2f(zp[1]);
  float g0 = o0 * siluf(z0);
  float g1 = o1 * siluf(z1);
  float ss = g0 * g0 + g1 * g1;
#pragma unroll
  for (int m = 1; m < 64; m <<= 1) ss += __shfl_xor(ss, m, 64);
  float sc = rsqrtf(ss * (1.f / 128.f) + 1e-6f);
  int e = l * 2;
  *(u32*)zp = pack2(g0 * sc * norm_w[e], g1 * sc * norm_w[e + 1]);
}

// -------- diagnostic: encode ws_size into d_out[0] --------------------------
__global__ void diag_kernel(float* out, float val) { out[0] = val; }

extern "C" void kernel_launch(void* const* d_in, const int* in_sizes, int n_in,
                              void* d_out, int out_size, void* d_ws,
                              size_t ws_size, hipStream_t stream) {
  const float* hidden = (const float*)d_in[1];
  const float* residual = (const float*)d_in[2];
  const float* ln_in_w = (const float*)d_in[3];
  const float* ln_post_w = (const float*)d_in[4];
  const float* Wqkvz = (const float*)d_in[5];
  const float* Wba = (const float*)d_in[6];
  const float* conv_w = (const float*)d_in[7];
  const float* A_log = (const float*)d_in[8];
  const float* dt_bias = (const float*)d_in[9];
  const float* norm_w = (const float*)d_in[10];
  const float* Wout = (const float*)d_in[11];
  const float* Wgate = (const float*)d_in[12];
  const float* Wup = (const float*)d_in[13];
  const float* Wdown = (const float*)d_in[14];

  char* ws = (char*)d_ws;
  size_t off = 0;
  auto alloc = [&](size_t n) {
    char* p = ws + off;
    off = (off + n + 255) & ~(size_t)255;
    return p;
  };
  u16* wslot = (u16*)alloc((size_t)INTER * DMODEL * 2);       // 33.55 MB
  u16* hb = (u16*)alloc((size_t)BT * DMODEL * 2);             //  8.39 MB
  u16* qkvb = (u16*)alloc((size_t)BT * CONVC * 2);            // 33.55 MB
  u16* zb = (u16*)alloc((size_t)BT * VALDIM * 2);             // 16.78 MB
  u16* qkvc = (u16*)alloc((size_t)BT * CONVC * 2);            // 33.55 MB
  float* ba = (float*)alloc((size_t)BT * 64 * 4);             //  0.52 MB
  float* bdpack = (float*)alloc((size_t)64 * 1024 * 2 * 4);   //  0.52 MB
  u16* obf = (u16*)alloc((size_t)BT * VALDIM * 2);            // 16.78 MB
  if (off > ws_size) {                                        // ~143.7 MB total
    diag_kernel<<<1, 1, 0, stream>>>((float*)d_out, (float)(ws_size >> 20));
    return;
  }

  float* res1 = (float*)d_out;                        // part1 (dead before out)
  float* attn = (float*)d_out + (size_t)BT * DMODEL;  // part2
  float* res2 = attn;                                 // in-place
  u16* h2b = hb;                                      // hb dead after GEMM1/ba
  u16* gbuf = qkvc;                                   // qkvc dead after scan
  u16* ubuf = qkvb;                                   // qkvb dead after conv
  u16* mbuf = qkvb;                                   // up GEMM writes m directly
  float* outp = (float*)d_out;                        // final (res1 dead)

  // chunked-scan prep outputs live in dead qkvb (exact fit) + ba regions
  u16* Tg = qkvb;                                     // 1024 x 4096 u16
  u16* Pg = qkvb + (size_t)1024 * 4096;               // 1024 x 4096 u16
  u16* KtTg = qkvb + (size_t)2 * 1024 * 4096;         // 1024 x 8192 u16
  float* Bvec = ba;                                   // 1024 x 64 f32

  dim3 blk(256);

  // 1. res1 = hidden+residual; hb = rmsnorm(res1)
  resnorm_kernel<<<BT, blk, 0, stream>>>(hidden, residual, ln_in_w, res1, hb);

  // 2. qkv-slice GEMM: qkvb = hb @ Wqkvz[:, :8192]
  convert_transpose<<<dim3(CONVC / 32, DMODEL / 32), blk, 0, stream>>>(
      Wqkvz, QKVZ_N, wslot, DMODEL, CONVC);
  gemm_kernel<1><<<dim3(CONVC / 128, BT / 128), blk, 0, stream>>>(
      hb, wslot, qkvb, nullptr, BT, CONVC, DMODEL);

  // 3. z-slice GEMM: zb = hb @ Wqkvz[:, 8192:]
  convert_transpose<<<dim3(VALDIM / 32, DMODEL / 32), blk, 0, stream>>>(
      Wqkvz + CONVC, QKVZ_N, wslot, DMODEL, VALDIM);
  gemm_kernel<1><<<dim3(VALDIM / 128, BT / 128), blk, 0, stream>>>(
      hb, wslot, zb, nullptr, BT, VALDIM, DMODEL);

  // 4. ba = hb @ Wba
  ba_gemm_kernel<<<BT, blk, 0, stream>>>(hb, Wba, ba);

  // 5-7. conv+silu, l2norm(q,k), beta/decay (packed per-head layout)
  conv_silu_kernel<<<BT * 2048 / 256, blk, 0, stream>>>(qkvb, conv_w, qkvc);
  l2norm_kernel<<<BT * 32 / 4, blk, 0, stream>>>(qkvc);
  betadecay_kernel<<<BT * HV / 256, blk, 0, stream>>>(ba, A_log, dt_bias,
                                                      bdpack);

  // 8. chunked gated delta rule scan (prep parallel, then sequential-in-chunk)
  prep_kernel<<<dim3(16, 64), blk, 0, stream>>>(qkvc, bdpack, Tg, Pg, KtTg,
                                                Bvec);
  chunk_scan_kernel<<<dim3(4, 64), dim3(512), 0, stream>>>(
      qkvc, bdpack, Tg, Pg, KtTg, Bvec, obf);

  // 9. gate + per-head RMSNorm (in place over zb)
  gatenorm_kernel<<<BT * HV / 4, blk, 0, stream>>>(obf, zb, norm_w);

  // 10. attn = og @ Wout  (f32, into d_out part2)
  convert_transpose<<<dim3(DMODEL / 32, VALDIM / 32), blk, 0, stream>>>(
      Wout, DMODEL, wslot, VALDIM, DMODEL);
  gemm_kernel<0><<<dim3(DMODEL / 128, BT / 128), blk, 0, stream>>>(
      zb, wslot, attn, nullptr, BT, DMODEL, VALDIM);

  // 11. res2 = attn + res1 (in place, part2); h2b = rmsnorm(res2)
  resnorm_kernel<<<BT, blk, 0, stream>>>(attn, res1, ln_post_w, res2, h2b);

  // 12. gate GEMM (bf16 out)
  convert_transpose<<<dim3(INTER / 32, DMODEL / 32), blk, 0, stream>>>(
      Wgate, INTER, wslot, DMODEL, INTER);
  gemm_kernel<1><<<dim3(INTER / 128, BT / 128), blk, 0, stream>>>(
      h2b, wslot, gbuf, nullptr, BT, INTER, DMODEL);

  // 13. up GEMM fused with m = silu(g)*u (writes mbuf directly)
  convert_transpose<<<dim3(INTER / 32, DMODEL / 32), blk, 0, stream>>>(
      Wup, INTER, wslot, DMODEL, INTER);
  gemm_kernel<2><<<dim3(INTER / 128, BT / 128), blk, 0, stream>>>(
      h2b, wslot, mbuf, gbuf, BT, INTER, DMODEL);

  // 14. out = m @ Wdown (f32, d_out part1)
  convert_transpose<<<dim3(DMODEL / 32, INTER / 32), blk, 0, stream>>>(
      Wdown, DMODEL, wslot, INTER, DMODEL);
  gemm_kernel<0><<<dim3(DMODEL / 128, BT / 128), blk, 0, stream>>>(
      mbuf, wslot, outp, nullptr, BT, DMODEL, INTER);
}

// Round 8
// 901.417 us; speedup vs baseline: 1.7973x; 1.0838x over previous
//
#include <hip/hip_runtime.h>
#include <hip/hip_bf16.h>

typedef unsigned short u16;
typedef unsigned int u32;
typedef float f32x4 __attribute__((ext_vector_type(4)));
typedef short bf16x8 __attribute__((ext_vector_type(8)));
typedef unsigned short u16x4 __attribute__((ext_vector_type(4)));
typedef unsigned int u32x2 __attribute__((ext_vector_type(2)));
typedef unsigned int u32x4 __attribute__((ext_vector_type(4)));

#define BT 2048            // B*T
#define DMODEL 2048
#define HV 32
#define DK 128
#define KEYDIM 2048
#define VALDIM 4096
#define QKVZ_N 12288
#define CONVC 8192         // q,k,v channels
#define INTER 8192

__device__ __forceinline__ float bf2f(u16 v) {
  u32 u = ((u32)v) << 16;
  return __builtin_bit_cast(float, u);
}
__device__ __forceinline__ u16 f2bf(float f) {
  u32 u = __builtin_bit_cast(u32, f);
  u32 r = (u + 0x7fffu + ((u >> 16) & 1u)) >> 16;
  return (u16)r;
}
__device__ __forceinline__ u32 pack2(float a, float b) {
  return (u32)f2bf(a) | ((u32)f2bf(b) << 16);
}
__device__ __forceinline__ float siluf(float x) {
  return x / (1.f + expf(-x));
}

// -------- weight convert+transpose: W[K,N] f32 (row stride ldw) -> Wt[N,K] bf16
__global__ __launch_bounds__(256) void convert_transpose(
    const float* __restrict__ W, int ldw, u16* __restrict__ Wt, int K, int N) {
  __shared__ float tile[32][33];
  int n0 = blockIdx.x * 32, k0 = blockIdx.y * 32;
  int tx = threadIdx.x & 31, ty = threadIdx.x >> 5;  // ty 0..7
#pragma unroll
  for (int i = 0; i < 4; ++i) {
    int kk = ty + i * 8;
    tile[kk][tx] = W[(size_t)(k0 + kk) * ldw + n0 + tx];
  }
  __syncthreads();
#pragma unroll
  for (int i = 0; i < 4; ++i) {
    int nn = ty + i * 8;
    Wt[(size_t)(n0 + nn) * K + k0 + tx] = f2bf(tile[tx][nn]);
  }
}

// -------- fused residual add + gemma RMSNorm (a+b -> resout f32, norm -> bf16)
__global__ __launch_bounds__(256) void resnorm_kernel(
    const float* __restrict__ a, const float* __restrict__ b,
    const float* __restrict__ w, float* __restrict__ resout,
    u16* __restrict__ hb) {
  int tok = blockIdx.x, t = threadIdx.x;
  const float* ap = a + (size_t)tok * DMODEL + t * 8;
  const float* bp = b + (size_t)tok * DMODEL + t * 8;
  f32x4 x0 = *(const f32x4*)ap + *(const f32x4*)bp;
  f32x4 x1 = *(const f32x4*)(ap + 4) + *(const f32x4*)(bp + 4);
  *(f32x4*)(resout + (size_t)tok * DMODEL + t * 8) = x0;
  *(f32x4*)(resout + (size_t)tok * DMODEL + t * 8 + 4) = x1;
  float ss = 0.f;
#pragma unroll
  for (int j = 0; j < 4; ++j) ss += x0[j] * x0[j] + x1[j] * x1[j];
#pragma unroll
  for (int m = 1; m < 64; m <<= 1) ss += __shfl_xor(ss, m, 64);
  __shared__ float red[4];
  if ((t & 63) == 0) red[t >> 6] = ss;
  __syncthreads();
  ss = red[0] + red[1] + red[2] + red[3];
  float sc = rsqrtf(ss * (1.f / (float)DMODEL) + 1e-6f);
  const float* wp = w + t * 8;
  float y[8];
#pragma unroll
  for (int j = 0; j < 4; ++j) {
    y[j] = x0[j] * sc * (1.f + wp[j]);
    y[4 + j] = x1[j] * sc * (1.f + wp[4 + j]);
  }
  u32x4 st;
  st[0] = pack2(y[0], y[1]);
  st[1] = pack2(y[2], y[3]);
  st[2] = pack2(y[4], y[5]);
  st[3] = pack2(y[6], y[7]);
  *(u32x4*)(hb + (size_t)tok * DMODEL + t * 8) = st;
}

// -------- bf16 MFMA GEMM: C[M,N] = A[M,K]_bf16 * Bt[N,K]^T ------------------
// OUT: 0=f32 out (+ split-K partial slice per blockIdx.z), 1=bf16 out,
//      2=bf16 out of silu(Aux)*acc (fused SwiGLU).
// Depth-4 LDS ring, counted vmcnt (8/4/0) + raw s_barrier: 3 tiles in flight,
// 1 barrier per K-step. Rasterization: bijective XCD chunk + group-major GRP=4.
__device__ __forceinline__ void async16(const void* g, void* l) {
  __builtin_amdgcn_global_load_lds(
      (const __attribute__((address_space(1))) u32*)g,
      (__attribute__((address_space(3))) u32*)l, 16, 0, 0);
}

template <int OUT>
__global__ __launch_bounds__(256) void gemm_kernel(
    const u16* __restrict__ A, const u16* __restrict__ Bt,
    void* __restrict__ Cv, const u16* __restrict__ Aux, int M, int N,
    int Kfull, int Ks) {
  __shared__ __align__(16) u16 Al[4][128 * 32];
  __shared__ __align__(16) u16 Bl[4][128 * 32];
  int tid = threadIdx.x;
  int w = tid >> 6, l = tid & 63;
  int wr = w >> 1, wc = w & 1;
  int r15 = l & 15, kb = l >> 4;

  // ---- rasterization (x,y only; z = K-slice)
  int nbx = gridDim.x, nby = gridDim.y;
  int bid = blockIdx.y * nbx + blockIdx.x;
  int nwg = nbx * nby;
  int cpx = nwg >> 3;
  int wg = (bid & 7) * cpx + (bid >> 3);
  const int GRP = 4;  // nbx % 4 == 0 in all launches
  int span = GRP * nby;
  int grpId = wg / span;
  int rem = wg - grpId * span;
  int n0 = (grpId * GRP + (rem % GRP)) * 128;
  int m0 = (rem / GRP) * 128;
  int kbase = blockIdx.z * Ks;

  f32x4 acc[4][4] = {};

  auto stage = [&](int buf, int kt) {
#pragma unroll
    for (int c = 0; c < 2; ++c) {
      int gid = w * 128 + c * 64 + l;          // 16B granule id in tile
      int row = gid >> 2;
      int g = (gid & 3) ^ ((row >> 1) & 3);    // pre-swizzled source granule
      async16(A + (size_t)(m0 + row) * Kfull + kt + g * 8, Al[buf] + gid * 8);
      async16(Bt + (size_t)(n0 + row) * Kfull + kt + g * 8, Bl[buf] + gid * 8);
    }
  };

  int nst = Ks >> 5;
#pragma unroll
  for (int p = 0; p < 3; ++p)
    if (p < nst) stage(p & 3, kbase + p * 32);

  for (int i = 0; i < nst; ++i) {
    int issued = (i + 3 < nst) ? (i + 3) : nst;
    int infl = issued - i - 1;  // tiles still in flight beyond buf i (0..2)
    if (infl >= 2)
      asm volatile("s_waitcnt vmcnt(8)" ::: "memory");
    else if (infl == 1)
      asm volatile("s_waitcnt vmcnt(4)" ::: "memory");
    else
      asm volatile("s_waitcnt vmcnt(0)" ::: "memory");
    __builtin_amdgcn_s_barrier();        // buf i ready everywhere; prev reads done
    __builtin_amdgcn_sched_barrier(0);
    if (i + 3 < nst) stage((i + 3) & 3, kbase + (i + 3) * 32);
    const u16* Ac = Al[i & 3];
    const u16* Bc = Bl[i & 3];
    bf16x8 aF[4], bF[4];
#pragma unroll
    for (int m = 0; m < 4; ++m) {
      int row = wr * 64 + m * 16 + r15;
      aF[m] = *(const bf16x8*)(Ac + row * 32 + (kb ^ ((row >> 1) & 3)) * 8);
    }
#pragma unroll
    for (int n = 0; n < 4; ++n) {
      int row = wc * 64 + n * 16 + r15;
      bF[n] = *(const bf16x8*)(Bc + row * 32 + (kb ^ ((row >> 1) & 3)) * 8);
    }
#pragma unroll
    for (int m = 0; m < 4; ++m)
#pragma unroll
      for (int n = 0; n < 4; ++n)
        acc[m][n] = __builtin_amdgcn_mfma_f32_16x16x32_bf16(aF[m], bF[n],
                                                            acc[m][n], 0, 0, 0);
  }

  float* Cf = (float*)Cv + (size_t)blockIdx.z * M * N;  // split-K partial slice
#pragma unroll
  for (int m = 0; m < 4; ++m)
#pragma unroll
    for (int n = 0; n < 4; ++n) {
      size_t base = (size_t)(m0 + wr * 64 + m * 16 + kb * 4) * N +
                    (n0 + wc * 64 + n * 16 + r15);
#pragma unroll
      for (int r = 0; r < 4; ++r) {
        size_t idx = base + (size_t)r * N;
        if (OUT == 0)
          Cf[idx] = acc[m][n][r];
        else if (OUT == 1)
          ((u16*)Cv)[idx] = f2bf(acc[m][n][r]);
        else
          ((u16*)Cv)[idx] = f2bf(siluf(bf2f(Aux[idx])) * acc[m][n][r]);
      }
    }
}

// -------- split-K reduce: out[i] = sum_s parts[s*n + i] ---------------------
__global__ __launch_bounds__(256) void reduce_kernel(
    const float* __restrict__ p, float* __restrict__ o, int n, int S) {
  int i = (blockIdx.x * 256 + threadIdx.x) * 4;
  f32x4 s = *(const f32x4*)(p + i);
  for (int j = 1; j < S; ++j) s += *(const f32x4*)(p + (size_t)j * n + i);
  *(f32x4*)(o + i) = s;
}

// -------- ba = hb(bf16) @ Wba(f32 [2048,64]) --------------------------------
__global__ __launch_bounds__(256) void ba_gemm_kernel(
    const u16* __restrict__ hb, const float* __restrict__ Wba,
    float* __restrict__ ba) {
  int m = blockIdx.x;
  int t = threadIdx.x;
  int n = t & 63, kq = t >> 6;
  const u16* a = hb + (size_t)m * DMODEL + kq * 512;
  const float* wp = Wba + (size_t)kq * 512 * 64 + n;
  float sum = 0.f;
  for (int i = 0; i < 512; ++i)
    sum += bf2f(a[i]) * wp[(size_t)i * 64];
  __shared__ float red[256];
  red[t] = sum;
  __syncthreads();
  if (t < 64)
    ba[(size_t)m * 64 + t] = red[t] + red[t + 64] + red[t + 128] + red[t + 192];
}

// -------- causal depthwise conv (K=4) + SiLU, bf16 in/out -------------------
__global__ __launch_bounds__(256) void conv_silu_kernel(
    const u16* __restrict__ qkvb, const float* __restrict__ conv_w,
    u16* __restrict__ qkv) {
  int gid = blockIdx.x * 256 + threadIdx.x;  // BT * 2048 threads
  int c4 = (gid & 2047) * 4;
  int bt = gid >> 11;
  int b = bt >> 10, tt = bt & 1023;
  f32x4 wv[4];
#pragma unroll
  for (int j = 0; j < 4; ++j) wv[j] = *(const f32x4*)(conv_w + (c4 + j) * 4);
  float acc[4] = {0.f, 0.f, 0.f, 0.f};
#pragma unroll
  for (int i = 0; i < 4; ++i) {
    int ts = tt - 3 + i;
    if (ts >= 0) {
      u16x4 x = *(const u16x4*)(qkvb + (size_t)(b * 1024 + ts) * CONVC + c4);
#pragma unroll
      for (int j = 0; j < 4; ++j) acc[j] += bf2f(x[j]) * wv[j][i];
    }
  }
  u32x2 st;
  st[0] = pack2(siluf(acc[0]), siluf(acc[1]));
  st[1] = pack2(siluf(acc[2]), siluf(acc[3]));
  *(u32x2*)(qkv + (size_t)bt * CONVC + c4) = st;
}

// -------- l2 norm of q,k heads in place (bf16), q also * DK^-0.5 ------------
__global__ __launch_bounds__(256) void l2norm_kernel(u16* __restrict__ qkv) {
  int wid = blockIdx.x * 4 + (threadIdx.x >> 6);
  int l = threadIdx.x & 63;
  int tok = wid >> 5, slot = wid & 31;  // slot<16: q head, else k head
  u16* p = qkv + (size_t)tok * CONVC + slot * 128 + l * 2;
  float x0 = bf2f(p[0]), x1 = bf2f(p[1]);
  float ss = x0 * x0 + x1 * x1;
#pragma unroll
  for (int m = 1; m < 64; m <<= 1) ss += __shfl_xor(ss, m, 64);
  float sc = rsqrtf(ss + 1e-6f);
  if (slot < 16) sc *= 0.08838834764831845f;  // DK^-0.5
  *(u32*)p = pack2(x0 * sc, x1 * sc);
}

// -------- bd[(b*32+h)][t][2] = {sigmoid(bb), exp(-exp(A_log)*softplus)} -----
__global__ __launch_bounds__(256) void betadecay_kernel(
    const float* __restrict__ ba, const float* __restrict__ A_log,
    const float* __restrict__ dt_bias, float* __restrict__ bd) {
  int idx = blockIdx.x * 256 + threadIdx.x;  // BT*HV
  int h = idx & 31;
  int tok = idx >> 5;
  int b = tok >> 10, tt = tok & 1023;
  float bb = ba[(size_t)tok * 64 + h];
  float aa = ba[(size_t)tok * 64 + 32 + h];
  float bet = 1.f / (1.f + expf(-bb));
  float x = aa + dt_bias[h];
  float sp = (x > 20.f) ? x : log1pf(expf(x));
  float dec = expf(-expf(A_log[h]) * sp);
  size_t o = (((size_t)(b * 32 + h)) * 1024 + tt) * 2;
  bd[o] = bet;
  bd[o + 1] = dec;
}

// ======================= chunked delta-rule scan ============================
__global__ __launch_bounds__(256) void prep_kernel(
    const u16* __restrict__ qkvc, const float* __restrict__ bdpack,
    u16* __restrict__ Tg, u16* __restrict__ Pg, u16* __restrict__ KtTg,
    float* __restrict__ Bvec) {
  __shared__ __align__(16) u16 Kl[64 * 128];
  __shared__ __align__(16) u16 Ql[64 * 128];
  __shared__ __align__(16) float Af[64 * 64];
  __shared__ __align__(16) float Tf[64 * 64];
  __shared__ float lgl[64], bl[64], betal[64];
  int tid = threadIdx.x;
  int w = tid >> 6, l = tid & 63;
  int r15 = l & 15, kb = l >> 4;
  int c = blockIdx.x, bh = blockIdx.y;
  int b = bh >> 5, h = bh & 31, hk = h >> 1;
  size_t tok0 = (size_t)b * 1024 + c * 64;
  int ch = bh * 16 + c;  // chunk-head index

  // stage K, Q tiles [64][128] bf16
#pragma unroll
  for (int rep = 0; rep < 4; ++rep) {
    int gid = w * 256 + rep * 64 + l;
    int row = gid >> 4, seg = gid & 15;
    const u16* srcq = qkvc + (tok0 + row) * CONVC + hk * 128 + seg * 8;
    async16(srcq, Ql + gid * 8);
    async16(srcq + KEYDIM, Kl + gid * 8);
  }
  if (tid < 64) {
    size_t o = ((size_t)bh * 1024 + c * 64 + tid) * 2;
    betal[tid] = bdpack[o];
    lgl[tid] = logf(fmaxf(bdpack[o + 1], 1e-30f));
  }
  __syncthreads();
  if (tid < 64) {
    float s = 0.f;
    for (int j = 0; j <= tid; ++j) s += lgl[j];
    bl[tid] = s;
    Bvec[(size_t)ch * 64 + tid] = expf(s);
  }
  __syncthreads();

  // KK^T -> A (f32 LDS, strict lower, scaled); QK^T -> P (bf16 global)
  {
    f32x4 akk[4] = {}, aqk[4] = {};
#pragma unroll
    for (int ks = 0; ks < 4; ++ks) {
      bf16x8 kaF = *(const bf16x8*)(Kl + (w * 16 + r15) * 128 + ks * 32 + kb * 8);
      bf16x8 qaF = *(const bf16x8*)(Ql + (w * 16 + r15) * 128 + ks * 32 + kb * 8);
#pragma unroll
      for (int n = 0; n < 4; ++n) {
        bf16x8 bF = *(const bf16x8*)(Kl + (n * 16 + r15) * 128 + ks * 32 + kb * 8);
        akk[n] = __builtin_amdgcn_mfma_f32_16x16x32_bf16(kaF, bF, akk[n], 0, 0, 0);
        aqk[n] = __builtin_amdgcn_mfma_f32_16x16x32_bf16(qaF, bF, aqk[n], 0, 0, 0);
      }
    }
#pragma unroll
    for (int n = 0; n < 4; ++n)
#pragma unroll
      for (int r = 0; r < 4; ++r) {
        int i = w * 16 + kb * 4 + r;
        int j = n * 16 + r15;
        float e = expf(bl[i] - bl[j]);  // only used when j<=i (<=0 exponent)
        Af[i * 64 + j] = (j < i) ? betal[i] * e * akk[n][r] : 0.f;
        u16 pv = (j <= i) ? f2bf(e * aqk[n][r]) : (u16)0;
        Pg[(size_t)ch * 4096 + i * 64 + j] = pv;
      }
  }
  // KtT[d][j] = exp(b63-b_j) * K[j][d]  (bf16 global [128][64])
  float b63 = bl[63];
  for (int m = 0; m < 32; ++m) {
    int idx = tid * 32 + m;
    int d = idx >> 6, j = idx & 63;
    float v = bf2f(Kl[j * 128 + d]) * expf(b63 - bl[j]);
    KtTg[(size_t)ch * 8192 + idx] = f2bf(v);
  }
  __syncthreads();
  // T = I
#pragma unroll
  for (int m = 0; m < 16; ++m) Tf[tid * 16 + m] = 0.f;
  __syncthreads();
  if (tid < 64) Tf[tid * 65] = 1.f;
  __syncthreads();
  // forward substitution: wave w owns 16 columns, 4-way k-partials per column
  {
    int ccol = w * 16 + r15;
    int p = kb;
    for (int i = 1; i < 64; ++i) {
      float part = 0.f;
      for (int j = p; j < i; j += 4) part += Af[i * 64 + j] * Tf[j * 64 + ccol];
      part += __shfl_xor(part, 16, 64);
      part += __shfl_xor(part, 32, 64);
      if (p == 0) Tf[i * 64 + ccol] = ((ccol == i) ? 1.f : 0.f) - part;
    }
  }
  __syncthreads();
#pragma unroll
  for (int m = 0; m < 16; ++m) {
    int idx = tid * 16 + m;
    Tg[(size_t)ch * 4096 + idx] = f2bf(Tf[idx]);
  }
}

__global__ __launch_bounds__(512) void chunk_scan_kernel(
    const u16* __restrict__ qkvc, const float* __restrict__ bdpack,
    const u16* __restrict__ Tg, const u16* __restrict__ Pg,
    const u16* __restrict__ KtTg, const float* __restrict__ Bvec,
    u16* __restrict__ obf) {
  __shared__ __align__(16) u16 Kl[64 * 128];
  __shared__ __align__(16) u16 Ql[64 * 128];
  __shared__ __align__(16) u16 KtTl[128 * 64];
  __shared__ __align__(16) u16 Tl[64 * 64];
  __shared__ __align__(16) u16 Pl[64 * 64];
  __shared__ __align__(16) u16 Vl[64 * 32];
  __shared__ __align__(16) u16 St[32 * 128];
  __shared__ __align__(16) u16 rhsT[32 * 64];
  __shared__ __align__(16) u16 dT[32 * 64];
  __shared__ float betal[64], Gl[64];

  int tid = threadIdx.x;
  int w = tid >> 6, l = tid & 63;
  int r15 = l & 15, kb = l >> 4;
  int dvc = blockIdx.x, bh = blockIdx.y;
  int b = bh >> 5, h = bh & 31, hk = h >> 1;
  int a = w >> 1, bcol = w & 1;  // [64x32]-output tile: rows a*16.., cols bcol*16..

  for (int m = tid; m < 32 * 128; m += 512) St[m] = 0;
  f32x4 sAcc0 = {}, sAcc1 = {};
  __syncthreads();

  for (int c = 0; c < 16; ++c) {
    size_t tok0 = (size_t)b * 1024 + c * 64;
    int ch = bh * 16 + c;
    // ---- stage ----
#pragma unroll
    for (int rep = 0; rep < 2; ++rep) {
      int gid = w * 128 + rep * 64 + l;
      int row = gid >> 4, seg = gid & 15;
      const u16* srcq = qkvc + (tok0 + row) * CONVC + hk * 128 + seg * 8;
      async16(srcq, Ql + gid * 8);
      async16(srcq + KEYDIM, Kl + gid * 8);
      async16(KtTg + (size_t)ch * 8192 + gid * 8, KtTl + gid * 8);
    }
    {
      int gid = w * 64 + l;
      async16(Tg + (size_t)ch * 4096 + gid * 8, Tl + gid * 8);
      async16(Pg + (size_t)ch * 4096 + gid * 8, Pl + gid * 8);
    }
    if (w < 4) {
      int gid = w * 64 + l;  // 256 granules
      int row = gid >> 2, seg = gid & 3;
      async16(qkvc + (tok0 + row) * CONVC + 2 * KEYDIM + h * 128 + dvc * 32 + seg * 8,
              Vl + gid * 8);
    }
    if (tid < 64) {
      betal[tid] = bdpack[((size_t)bh * 1024 + c * 64 + tid) * 2];
      Gl[tid] = Bvec[(size_t)ch * 64 + tid];
    }
    __syncthreads();

    // ---- KS0 = K@S0, QS0 = Q@S0 ----
    f32x4 aKS = {}, aQS = {};
#pragma unroll
    for (int ks = 0; ks < 4; ++ks) {
      bf16x8 bF = *(const bf16x8*)(St + (bcol * 16 + r15) * 128 + ks * 32 + kb * 8);
      bf16x8 kF = *(const bf16x8*)(Kl + (a * 16 + r15) * 128 + ks * 32 + kb * 8);
      bf16x8 qF = *(const bf16x8*)(Ql + (a * 16 + r15) * 128 + ks * 32 + kb * 8);
      aKS = __builtin_amdgcn_mfma_f32_16x16x32_bf16(kF, bF, aKS, 0, 0, 0);
      aQS = __builtin_amdgcn_mfma_f32_16x16x32_bf16(qF, bF, aQS, 0, 0, 0);
    }
    // ---- rhsT[dv][i] = beta_i (v - B_i * KS0) ----
    {
      int i0 = a * 16 + kb * 4;
      int dv = bcol * 16 + r15;
      u16x4 st;
#pragma unroll
      for (int r = 0; r < 4; ++r) {
        int i = i0 + r;
        float v = bf2f(Vl[i * 32 + dv]);
        st[r] = f2bf(betal[i] * (v - Gl[i] * aKS[r]));
      }
      *(u16x4*)(rhsT + dv * 64 + i0) = st;
    }
    __syncthreads();
    // ---- delta = T @ rhs ----
    f32x4 aD = {};
#pragma unroll
    for (int ks = 0; ks < 2; ++ks) {
      bf16x8 aF = *(const bf16x8*)(Tl + (a * 16 + r15) * 64 + ks * 32 + kb * 8);
      bf16x8 bF = *(const bf16x8*)(rhsT + (bcol * 16 + r15) * 64 + ks * 32 + kb * 8);
      aD = __builtin_amdgcn_mfma_f32_16x16x32_bf16(aF, bF, aD, 0, 0, 0);
    }
    {
      int i0 = a * 16 + kb * 4;
      int dv = bcol * 16 + r15;
      u16x4 st;
#pragma unroll
      for (int r = 0; r < 4; ++r) st[r] = f2bf(aD[r]);
      *(u16x4*)(dT + dv * 64 + i0) = st;
    }
    __syncthreads();
    // ---- O = B.*QS0 + P @ delta -> global ----
    f32x4 aO = {};
#pragma unroll
    for (int ks = 0; ks < 2; ++ks) {
      bf16x8 aF = *(const bf16x8*)(Pl + (a * 16 + r15) * 64 + ks * 32 + kb * 8);
      bf16x8 bF = *(const bf16x8*)(dT + (bcol * 16 + r15) * 64 + ks * 32 + kb * 8);
      aO = __builtin_amdgcn_mfma_f32_16x16x32_bf16(aF, bF, aO, 0, 0, 0);
    }
    {
      int i0 = a * 16 + kb * 4;
      int dv = bcol * 16 + r15;
#pragma unroll
      for (int r = 0; r < 4; ++r) {
        int i = i0 + r;
        float o = aO[r] + Gl[i] * aQS[r];
        obf[(tok0 + i) * VALDIM + h * 128 + dvc * 32 + dv] = f2bf(o);
      }
    }
    // ---- state update: S = B63*S + KtT @ delta ----
    float gL = Gl[63];
#pragma unroll
    for (int r = 0; r < 4; ++r) { sAcc0[r] *= gL; sAcc1[r] *= gL; }
#pragma unroll
    for (int ks = 0; ks < 2; ++ks) {
      bf16x8 aF = *(const bf16x8*)(KtTl + (w * 16 + r15) * 64 + ks * 32 + kb * 8);
      bf16x8 b0 = *(const bf16x8*)(dT + r15 * 64 + ks * 32 + kb * 8);
      bf16x8 b1 = *(const bf16x8*)(dT + (16 + r15) * 64 + ks * 32 + kb * 8);
      sAcc0 = __builtin_amdgcn_mfma_f32_16x16x32_bf16(aF, b0, sAcc0, 0, 0, 0);
      sAcc1 = __builtin_amdgcn_mfma_f32_16x16x32_bf16(aF, b1, sAcc1, 0, 0, 0);
    }
#pragma unroll
    for (int r = 0; r < 4; ++r) {
      int dk = w * 16 + kb * 4 + r;
      St[r15 * 128 + dk] = f2bf(sAcc0[r]);
      St[(16 + r15) * 128 + dk] = f2bf(sAcc1[r]);
    }
    __syncthreads();
  }
}

// -------- gate (silu(z)) + per-head RMSNorm, in-place over z ----------------
__global__ __launch_bounds__(256) void gatenorm_kernel(
    const u16* __restrict__ obf, u16* __restrict__ zb,
    const float* __restrict__ norm_w) {
  int wid = blockIdx.x * 4 + (threadIdx.x >> 6);
  int l = threadIdx.x & 63;
  int tok = wid >> 5, h = wid & 31;
  const u16* op = obf + (size_t)tok * VALDIM + h * 128 + l * 2;
  u16* zp = zb + (size_t)tok * VALDIM + h * 128 + l * 2;
  float o0 = bf2f(op[0]), o1 = bf2f(op[1]);
  float z0 = bf2f(zp[0]), z1 = bf2f(zp[1]);
  float g0 = o0 * siluf(z0);
  float g1 = o1 * siluf(z1);
  float ss = g0 * g0 + g1 * g1;
#pragma unroll
  for (int m = 1; m < 64; m <<= 1) ss += __shfl_xor(ss, m, 64);
  float sc = rsqrtf(ss * (1.f / 128.f) + 1e-6f);
  int e = l * 2;
  *(u32*)zp = pack2(g0 * sc * norm_w[e], g1 * sc * norm_w[e + 1]);
}

// -------- diagnostic: encode ws_size into d_out[0] --------------------------
__global__ void diag_kernel(float* out, float val) { out[0] = val; }

extern "C" void kernel_launch(void* const* d_in, const int* in_sizes, int n_in,
                              void* d_out, int out_size, void* d_ws,
                              size_t ws_size, hipStream_t stream) {
  const float* hidden = (const float*)d_in[1];
  const float* residual = (const float*)d_in[2];
  const float* ln_in_w = (const float*)d_in[3];
  const float* ln_post_w = (const float*)d_in[4];
  const float* Wqkvz = (const float*)d_in[5];
  const float* Wba = (const float*)d_in[6];
  const float* conv_w = (const float*)d_in[7];
  const float* A_log = (const float*)d_in[8];
  const float* dt_bias = (const float*)d_in[9];
  const float* norm_w = (const float*)d_in[10];
  const float* Wout = (const float*)d_in[11];
  const float* Wgate = (const float*)d_in[12];
  const float* Wup = (const float*)d_in[13];
  const float* Wdown = (const float*)d_in[14];

  char* ws = (char*)d_ws;
  size_t off = 0;
  auto alloc = [&](size_t n) {
    char* p = ws + off;
    off = (off + n + 255) & ~(size_t)255;
    return p;
  };
  u16* wslot = (u16*)alloc((size_t)INTER * DMODEL * 2);       // 33.55 MB
  u16* hb = (u16*)alloc((size_t)BT * DMODEL * 2);             //  8.39 MB
  u16* qkvb = (u16*)alloc((size_t)BT * CONVC * 2);            // 33.55 MB
  u16* zb = (u16*)alloc((size_t)BT * VALDIM * 2);             // 16.78 MB
  u16* qkvc = (u16*)alloc((size_t)BT * CONVC * 2);            // 33.55 MB
  float* ba = (float*)alloc((size_t)BT * 64 * 4);             //  0.52 MB
  float* bdpack = (float*)alloc((size_t)64 * 1024 * 2 * 4);   //  0.52 MB
  u16* obf = (u16*)alloc((size_t)BT * VALDIM * 2);            // 16.78 MB
  if (off > ws_size) {                                        // ~143.7 MB total
    diag_kernel<<<1, 1, 0, stream>>>((float*)d_out, (float)(ws_size >> 20));
    return;
  }

  float* res1 = (float*)d_out;                        // part1 (dead before out)
  float* attn = (float*)d_out + (size_t)BT * DMODEL;  // part2
  float* res2 = attn;                                 // in-place
  u16* h2b = hb;                                      // hb dead after GEMM1/ba
  u16* gbuf = qkvc;                                   // qkvc dead after scan
  u16* mbuf = qkvb;                                   // up GEMM writes m directly
  float* outp = (float*)d_out;                        // final (res1 dead)

  // chunked-scan prep outputs live in dead qkvb (exact fit) + ba regions
  u16* Tg = qkvb;                                     // 1024 x 4096 u16
  u16* Pg = qkvb + (size_t)1024 * 4096;               // 1024 x 4096 u16
  u16* KtTg = qkvb + (size_t)2 * 1024 * 4096;         // 1024 x 8192 u16
  float* Bvec = ba;                                   // 1024 x 64 f32

  // split-K partials (dead-region reuse):
  float* pWout = (float*)qkvb;  // 2 x 2048x2048 f32 = 33.55 MB (qkvb dead)
  float* pDown = (float*)zb;    // 4 x 2048x2048 f32 = 67.1 MB (zb..obf dead)

  dim3 blk(256);

  // 1. res1 = hidden+residual; hb = rmsnorm(res1)
  resnorm_kernel<<<BT, blk, 0, stream>>>(hidden, residual, ln_in_w, res1, hb);

  // 2. qkv-slice GEMM: qkvb = hb @ Wqkvz[:, :8192]
  convert_transpose<<<dim3(CONVC / 32, DMODEL / 32), blk, 0, stream>>>(
      Wqkvz, QKVZ_N, wslot, DMODEL, CONVC);
  gemm_kernel<1><<<dim3(CONVC / 128, BT / 128), blk, 0, stream>>>(
      hb, wslot, qkvb, nullptr, BT, CONVC, DMODEL, DMODEL);

  // 3. z-slice GEMM: zb = hb @ Wqkvz[:, 8192:]
  convert_transpose<<<dim3(VALDIM / 32, DMODEL / 32), blk, 0, stream>>>(
      Wqkvz + CONVC, QKVZ_N, wslot, DMODEL, VALDIM);
  gemm_kernel<1><<<dim3(VALDIM / 128, BT / 128), blk, 0, stream>>>(
      hb, wslot, zb, nullptr, BT, VALDIM, DMODEL, DMODEL);

  // 4. ba = hb @ Wba
  ba_gemm_kernel<<<BT, blk, 0, stream>>>(hb, Wba, ba);

  // 5-7. conv+silu, l2norm(q,k), beta/decay (packed per-head layout)
  conv_silu_kernel<<<BT * 2048 / 256, blk, 0, stream>>>(qkvb, conv_w, qkvc);
  l2norm_kernel<<<BT * 32 / 4, blk, 0, stream>>>(qkvc);
  betadecay_kernel<<<BT * HV / 256, blk, 0, stream>>>(ba, A_log, dt_bias,
                                                      bdpack);

  // 8. chunked gated delta rule scan (prep parallel, then sequential-in-chunk)
  prep_kernel<<<dim3(16, 64), blk, 0, stream>>>(qkvc, bdpack, Tg, Pg, KtTg,
                                                Bvec);
  chunk_scan_kernel<<<dim3(4, 64), dim3(512), 0, stream>>>(
      qkvc, bdpack, Tg, Pg, KtTg, Bvec, obf);

  // 9. gate + per-head RMSNorm (in place over zb)
  gatenorm_kernel<<<BT * HV / 4, blk, 0, stream>>>(obf, zb, norm_w);

  // 10. attn = og @ Wout  (split-K=2 partials in dead qkvb, reduce to attn)
  convert_transpose<<<dim3(DMODEL / 32, VALDIM / 32), blk, 0, stream>>>(
      Wout, DMODEL, wslot, VALDIM, DMODEL);
  gemm_kernel<0><<<dim3(DMODEL / 128, BT / 128, 2), blk, 0, stream>>>(
      zb, wslot, pWout, nullptr, BT, DMODEL, VALDIM, VALDIM / 2);
  reduce_kernel<<<BT * DMODEL / 1024, blk, 0, stream>>>(pWout, attn,
                                                        BT * DMODEL, 2);

  // 11. res2 = attn + res1 (in place, part2); h2b = rmsnorm(res2)
  resnorm_kernel<<<BT, blk, 0, stream>>>(attn, res1, ln_post_w, res2, h2b);

  // 12. gate GEMM (bf16 out)
  convert_transpose<<<dim3(INTER / 32, DMODEL / 32), blk, 0, stream>>>(
      Wgate, INTER, wslot, DMODEL, INTER);
  gemm_kernel<1><<<dim3(INTER / 128, BT / 128), blk, 0, stream>>>(
      h2b, wslot, gbuf, nullptr, BT, INTER, DMODEL, DMODEL);

  // 13. up GEMM fused with m = silu(g)*u (writes mbuf directly)
  convert_transpose<<<dim3(INTER / 32, DMODEL / 32), blk, 0, stream>>>(
      Wup, INTER, wslot, DMODEL, INTER);
  gemm_kernel<2><<<dim3(INTER / 128, BT / 128), blk, 0, stream>>>(
      h2b, wslot, mbuf, gbuf, BT, INTER, DMODEL, DMODEL);

  // 14. out = m @ Wdown (split-K=4 partials in dead zb..obf, reduce to outp)
  convert_transpose<<<dim3(DMODEL / 32, INTER / 32), blk, 0, stream>>>(
      Wdown, DMODEL, wslot, INTER, DMODEL);
  gemm_kernel<0><<<dim3(DMODEL / 128, BT / 128, 4), blk, 0, stream>>>(
      mbuf, wslot, pDown, nullptr, BT, DMODEL, INTER, INTER / 4);
  reduce_kernel<<<BT * DMODEL / 1024, blk, 0, stream>>>(pDown, outp,
                                                        BT * DMODEL, 4);
}